// Round 3
// baseline (390.185 us; speedup 1.0000x reference)
//
#include <hip/hip_runtime.h>

#define NN 5000
#define NE 40000

typedef unsigned int u32;

__device__ __forceinline__ float siluf(float x) { return x / (1.f + __expf(-x)); }

__device__ __forceinline__ u32 f2bf_u(float f) {
  u32 x = __float_as_uint(f);
  return (x + 0x7FFFu + ((x >> 16) & 1u)) >> 16;  // RNE
}
__device__ __forceinline__ u32 packbf2(float lo, float hi) {
  return f2bf_u(lo) | (f2bf_u(hi) << 16);
}
__device__ __forceinline__ void unpack8(uint4 q, float* f) {
  f[0] = __uint_as_float(q.x << 16); f[1] = __uint_as_float(q.x & 0xFFFF0000u);
  f[2] = __uint_as_float(q.y << 16); f[3] = __uint_as_float(q.y & 0xFFFF0000u);
  f[4] = __uint_as_float(q.z << 16); f[5] = __uint_as_float(q.z & 0xFFFF0000u);
  f[6] = __uint_as_float(q.w << 16); f[7] = __uint_as_float(q.w & 0xFFFF0000u);
}
__device__ __forceinline__ float dot8f(const float* h, const float* w, float init) {
  float a = init;
#pragma unroll
  for (int k = 0; k < 8; k++) a = fmaf(h[k], w[k], a);
  return a;
}
__device__ __forceinline__ void mlp8(const float* ea, const float* __restrict__ W0,
                                     const float* __restrict__ b0, float* h) {
#pragma unroll
  for (int j = 0; j < 8; j++) {
    float a = b0[j];
#pragma unroll
    for (int i = 0; i < 8; i++) a += ea[i] * W0[i*8 + j];
    h[j] = siluf(a);
  }
}

// ---- geometry + all three radial-MLP hidden activations + in-degree counts ----
__global__ void k_geom(const float* __restrict__ coords, const int* __restrict__ eidx,
                       const float* __restrict__ ipW0, const float* __restrict__ ipb0,
                       const float* __restrict__ lyW0, const float* __restrict__ lyb0,
                       const float* __restrict__ etW0, const float* __restrict__ etb0,
                       float* __restrict__ sh, float* __restrict__ h_ip,
                       float* __restrict__ h_ly, float* __restrict__ h_et,
                       float* __restrict__ cnt) {
  int e = blockIdx.x * blockDim.x + threadIdx.x;
  if (e >= NE) return;
  int s = eidx[e], d = eidx[NE + e];
  float vx = coords[d*3+0] - coords[s*3+0];
  float vy = coords[d*3+1] - coords[s*3+1];
  float vz = coords[d*3+2] - coords[s*3+2];
  float dist = sqrtf(vx*vx + vy*vy + vz*vz + 1e-12f);
  float inv = 1.f / dist;
  const float SQ3 = 1.7320508075688772f;
  sh[e*3+0] = SQ3 * vy * inv;   // e3nn (y,z,x) order
  sh[e*3+1] = SQ3 * vz * inv;
  sh[e*3+2] = SQ3 * vx * inv;
  float ea[8];
  const float step = 5.f / 9.f;
#pragma unroll
  for (int j = 0; j < 8; j++) {
    float diff = (dist - step * (float)(j+1)) * (9.f / 5.f);
    ea[j] = __expf(-diff*diff) * (1.f / 1.12f);
  }
  float h[8];
  mlp8(ea, ipW0, ipb0, h);
#pragma unroll
  for (int j = 0; j < 8; j++) h_ip[e*8+j] = h[j];
  mlp8(ea, lyW0, lyb0, h);
#pragma unroll
  for (int j = 0; j < 8; j++) h_ly[e*8+j] = h[j];
  mlp8(ea, etW0, etb0, h);
#pragma unroll
  for (int j = 0; j < 8; j++) h_et[e*8+j] = h[j];
  atomicAdd(&cnt[d], 1.f);
}

// ---- embedding gather ----
__global__ void k_embed(const int* __restrict__ at, const float* __restrict__ emb,
                        float* __restrict__ s0) {
  int t = blockIdx.x * blockDim.x + threadIdx.x;
  if (t >= NN*32) return;
  s0[t] = emb[at[t >> 5]*32 + (t & 31)];
}

// ---- scalar-driven conv: paths {0,1}: out_s += c*Σ su*w0, out_v += c*sh_i*Σ su*w1 ----
// bf16 weights in LDS (32 KB) + fp32 biases (8 KB); 4 edges per 32-lane group pass.
__global__ __launch_bounds__(256, 4) void k_sconv(
    const float* __restrict__ hE, const float* __restrict__ sh,
    const float* __restrict__ sIn, const int* __restrict__ eidx,
    const float* __restrict__ W1, const float* __restrict__ b1,
    int ldw, float cscale,
    float* __restrict__ accS, float* __restrict__ accV) {
  __shared__ uint4 Wp[2048];   // [path*1024 + j], 8 bf16 k-values per entry
  __shared__ float2 Bp[1024];  // (b_path0[j], b_path1[j])
  for (int t = threadIdx.x; t < 2048; t += 256) {
    const float* s = W1 + t;   // col t (paths 0,1 occupy cols [0,2048))
    uint4 q;
    q.x = packbf2(s[0],       s[ldw]);
    q.y = packbf2(s[2*ldw],   s[3*ldw]);
    q.z = packbf2(s[4*ldw],   s[5*ldw]);
    q.w = packbf2(s[6*ldw],   s[7*ldw]);
    Wp[t] = q;
  }
  for (int t = threadIdx.x; t < 1024; t += 256)
    Bp[t] = make_float2(b1[t], b1[1024 + t]);
  __syncthreads();
  const int g = threadIdx.x >> 5, tw = threadIdx.x & 31;
  for (int p = blockIdx.x*8 + g; p*4 < NE; p += gridDim.x*8) {
    int e0 = p*4;
    float h[4][8];
#pragma unroll
    for (int a = 0; a < 4; a++) {
      float4 qa = *(const float4*)&hE[(e0+a)*8];
      float4 qb = *(const float4*)&hE[(e0+a)*8+4];
      h[a][0]=qa.x; h[a][1]=qa.y; h[a][2]=qa.z; h[a][3]=qa.w;
      h[a][4]=qb.x; h[a][5]=qb.y; h[a][6]=qb.z; h[a][7]=qb.w;
    }
    int dsts[4];
    float x[4];
#pragma unroll
    for (int a = 0; a < 4; a++) {
      dsts[a] = eidx[NE+e0+a];
      x[a] = sIn[eidx[e0+a]*32 + tw];
    }
    float as[4] = {0,0,0,0}, av[4] = {0,0,0,0};
#pragma unroll 8
    for (int u = 0; u < 32; u++) {
      int j = u*32 + tw;
      uint4 qs = Wp[j];
      uint4 qv = Wp[1024 + j];
      float2 bb = Bp[j];
      float fs[8], fv[8];
      unpack8(qs, fs);
      unpack8(qv, fv);
#pragma unroll
      for (int a = 0; a < 4; a++) {
        float su = __shfl(x[a], u, 32);
        as[a] = fmaf(su, dot8f(h[a], fs, bb.x), as[a]);
        av[a] = fmaf(su, dot8f(h[a], fv, bb.y), av[a]);
      }
    }
#pragma unroll
    for (int a = 0; a < 4; a++) {
      atomicAdd(&accS[dsts[a]*32 + tw], cscale*as[a]);
      float m = cscale*av[a];
      atomicAdd(&accV[dsts[a]*96 + tw*3 + 0], m*sh[(e0+a)*3+0]);
      atomicAdd(&accV[dsts[a]*96 + tw*3 + 1], m*sh[(e0+a)*3+1]);
      atomicAdd(&accV[dsts[a]*96 + tw*3 + 2], m*sh[(e0+a)*3+2]);
    }
  }
}

// ---- vector-driven conv (hidden paths {2,3}): out_v += c*Σ vu_i*w2, out_s += c*Σ du*w3 ----
__global__ __launch_bounds__(256, 4) void k_vconv(
    const float* __restrict__ hE, const float* __restrict__ sh,
    const float* __restrict__ vIn, const int* __restrict__ eidx,
    const float* __restrict__ W1, const float* __restrict__ b1,
    float* __restrict__ accS, float* __restrict__ accV) {
  __shared__ uint4 Wp[2048];
  __shared__ float2 Bp[1024];
  for (int t = threadIdx.x; t < 2048; t += 256) {
    const float* s = W1 + 2048 + t;   // paths {2,3}: cols [2048, 4096)
    uint4 q;
    q.x = packbf2(s[0],        s[4096]);
    q.y = packbf2(s[2*4096],   s[3*4096]);
    q.z = packbf2(s[4*4096],   s[5*4096]);
    q.w = packbf2(s[6*4096],   s[7*4096]);
    Wp[t] = q;
  }
  for (int t = threadIdx.x; t < 1024; t += 256)
    Bp[t] = make_float2(b1[2048 + t], b1[3072 + t]);
  __syncthreads();
  const int g = threadIdx.x >> 5, tw = threadIdx.x & 31;
  const float c = 0.125f;                 // 1/sqrt(64)
  const float is3 = 0.5773502691896258f;  // 1/sqrt(3)
  for (int p = blockIdx.x*8 + g; p*4 < NE; p += gridDim.x*8) {
    int e0 = p*4;
    float h[4][8];
#pragma unroll
    for (int a = 0; a < 4; a++) {
      float4 qa = *(const float4*)&hE[(e0+a)*8];
      float4 qb = *(const float4*)&hE[(e0+a)*8+4];
      h[a][0]=qa.x; h[a][1]=qa.y; h[a][2]=qa.z; h[a][3]=qa.w;
      h[a][4]=qb.x; h[a][5]=qb.y; h[a][6]=qb.z; h[a][7]=qb.w;
    }
    int dsts[4];
    float vx[4], vy[4], vz[4], dd[4];
#pragma unroll
    for (int a = 0; a < 4; a++) {
      int sa = eidx[e0+a];
      dsts[a] = eidx[NE+e0+a];
      vx[a] = vIn[sa*96 + tw*3 + 0];
      vy[a] = vIn[sa*96 + tw*3 + 1];
      vz[a] = vIn[sa*96 + tw*3 + 2];
      dd[a] = (vx[a]*sh[(e0+a)*3+0] + vy[a]*sh[(e0+a)*3+1] + vz[a]*sh[(e0+a)*3+2]) * is3;
    }
    float tvx[4] = {0,0,0,0}, tvy[4] = {0,0,0,0}, tvz[4] = {0,0,0,0}, ts[4] = {0,0,0,0};
#pragma unroll 8
    for (int u = 0; u < 32; u++) {
      int j = u*32 + tw;
      uint4 q2 = Wp[j];
      uint4 q3 = Wp[1024 + j];
      float2 bb = Bp[j];
      float f2[8], f3[8];
      unpack8(q2, f2);
      unpack8(q3, f3);
#pragma unroll
      for (int a = 0; a < 4; a++) {
        float w2 = dot8f(h[a], f2, bb.x);
        float w3 = dot8f(h[a], f3, bb.y);
        float ux = __shfl(vx[a], u, 32);
        float uy = __shfl(vy[a], u, 32);
        float uz = __shfl(vz[a], u, 32);
        float du = __shfl(dd[a], u, 32);
        tvx[a] = fmaf(ux, w2, tvx[a]);
        tvy[a] = fmaf(uy, w2, tvy[a]);
        tvz[a] = fmaf(uz, w2, tvz[a]);
        ts[a]  = fmaf(du, w3, ts[a]);
      }
    }
#pragma unroll
    for (int a = 0; a < 4; a++) {
      atomicAdd(&accS[dsts[a]*32 + tw], c*ts[a]);
      atomicAdd(&accV[dsts[a]*96 + tw*3 + 0], c*tvx[a]);
      atomicAdd(&accV[dsts[a]*96 + tw*3 + 1], c*tvy[a]);
      atomicAdd(&accV[dsts[a]*96 + tw*3 + 2], c*tvz[a]);
    }
  }
}

// ---- scatter-mean ----
__global__ void k_n1(const float* __restrict__ cnt, const float* __restrict__ accS,
                     const float* __restrict__ accV, float* __restrict__ s1,
                     float* __restrict__ v1) {
  int t = blockIdx.x * blockDim.x + threadIdx.x;
  if (t >= NN*32) return;
  float r = 1.f / fmaxf(cnt[t >> 5], 1.f);
  s1[t] = accS[t] * r;
  v1[t*3+0] = accV[t*3+0] * r;
  v1[t*3+1] = accV[t*3+1] * r;
  v1[t*3+2] = accV[t*3+2] * r;
}

// ---- mean + linear self-interaction ----
__global__ void k_n2(const float* __restrict__ cnt, const float* __restrict__ accS,
                     const float* __restrict__ accV, const float* __restrict__ s1,
                     const float* __restrict__ v1, const float* __restrict__ Ws,
                     const float* __restrict__ Wv, float* __restrict__ s2,
                     float* __restrict__ v2) {
  int t = blockIdx.x * blockDim.x + threadIdx.x;
  if (t >= NN*32) return;
  int n = t >> 5, w = t & 31;
  float r = 1.f / fmaxf(cnt[n], 1.f);
  const float lc = 0.17677669529663687f;  // 1/sqrt(32)
  float ss = 0.f, sv0 = 0.f, sv1 = 0.f, sv2 = 0.f;
#pragma unroll 8
  for (int u = 0; u < 32; u++) {
    ss += s1[n*32 + u] * Ws[u*32 + w];
    float wv = Wv[u*32 + w];
    sv0 += v1[n*96 + u*3 + 0] * wv;
    sv1 += v1[n*96 + u*3 + 1] * wv;
    sv2 += v1[n*96 + u*3 + 2] * wv;
  }
  s2[t] = accS[t]*r + lc*ss;
  v2[t*3+0] = accV[t*3+0]*r + lc*sv0;
  v2[t*3+1] = accV[t*3+1]*r + lc*sv1;
  v2[t*3+2] = accV[t*3+2]*r + lc*sv2;
}

// ---- edge output TP -> 5x0e; lanes = u, 4 edges per group pass ----
__global__ __launch_bounds__(256, 4) void k_e3(
    const float* __restrict__ hE, const float* __restrict__ sh,
    const float* __restrict__ s2, const float* __restrict__ v2,
    const int* __restrict__ eidx,
    const float* __restrict__ W1, const float* __restrict__ b1,
    float* __restrict__ out) {
  __shared__ uint4 WQ[640];   // [(w*4+p)*32 + u] : 8 bf16 k-values
  __shared__ float BQ[640];
  for (int t = threadIdx.x; t < 640; t += 256) {
    int u = t & 31, wp = t >> 5, p2 = wp & 3, w = wp >> 2;
    int col = p2*160 + u*5 + w;
    const float* s = W1 + col;
    uint4 q;
    q.x = packbf2(s[0],      s[640]);
    q.y = packbf2(s[1280],   s[1920]);
    q.z = packbf2(s[2560],   s[3200]);
    q.w = packbf2(s[3840],   s[4480]);
    WQ[t] = q;
    BQ[t] = b1[col];
  }
  __syncthreads();
  const int g = threadIdx.x >> 5, tw = threadIdx.x & 31;
  const float c = 0.08838834764831845f;   // 1/sqrt(128)
  const float is3 = 0.5773502691896258f;
  for (int p = blockIdx.x*8 + g; p*4 < NE; p += gridDim.x*8) {
    int e0 = p*4;
    float h[4][8];
    float xs[4], xd[4], ys[4], yd[4];
#pragma unroll
    for (int a = 0; a < 4; a++) {
      float4 qa = *(const float4*)&hE[(e0+a)*8];
      float4 qb = *(const float4*)&hE[(e0+a)*8+4];
      h[a][0]=qa.x; h[a][1]=qa.y; h[a][2]=qa.z; h[a][3]=qa.w;
      h[a][4]=qb.x; h[a][5]=qb.y; h[a][6]=qb.z; h[a][7]=qb.w;
      int sA = eidx[e0+a], dA = eidx[NE+e0+a];
      float s0v = sh[(e0+a)*3+0], s1v = sh[(e0+a)*3+1], s2v = sh[(e0+a)*3+2];
      xs[a] = s2[sA*32 + tw];
      xd[a] = (v2[sA*96+tw*3+0]*s0v + v2[sA*96+tw*3+1]*s1v + v2[sA*96+tw*3+2]*s2v) * is3;
      ys[a] = s2[dA*32 + tw];
      yd[a] = (v2[dA*96+tw*3+0]*s0v + v2[dA*96+tw*3+1]*s1v + v2[dA*96+tw*3+2]*s2v) * is3;
    }
    float part[4][5];
#pragma unroll
    for (int w = 0; w < 5; w++) {
      float f0[8], f1[8], f2[8], f3[8];
      unpack8(WQ[(w*4+0)*32 + tw], f0);
      unpack8(WQ[(w*4+1)*32 + tw], f1);
      unpack8(WQ[(w*4+2)*32 + tw], f2);
      unpack8(WQ[(w*4+3)*32 + tw], f3);
      float b0v = BQ[(w*4+0)*32 + tw];
      float b1v = BQ[(w*4+1)*32 + tw];
      float b2v = BQ[(w*4+2)*32 + tw];
      float b3v = BQ[(w*4+3)*32 + tw];
#pragma unroll
      for (int a = 0; a < 4; a++) {
        float w0 = dot8f(h[a], f0, b0v);
        float w1 = dot8f(h[a], f1, b1v);
        float w2 = dot8f(h[a], f2, b2v);
        float w3 = dot8f(h[a], f3, b3v);
        part[a][w] = xs[a]*w0 + xd[a]*w1 + ys[a]*w2 + yd[a]*w3;
      }
    }
#pragma unroll
    for (int off = 16; off > 0; off >>= 1)
#pragma unroll
      for (int a = 0; a < 4; a++)
#pragma unroll
        for (int w = 0; w < 5; w++)
          part[a][w] += __shfl_xor(part[a][w], off, 32);
    float outv = 0.f;
#pragma unroll
    for (int a = 0; a < 4; a++)
#pragma unroll
      for (int w = 0; w < 5; w++)
        if (tw == a*5 + w) outv = part[a][w];
    if (tw < 20) out[e0*5 + tw] = c * outv;
  }
}

// ---- node output MLP ----
__global__ void k_nodeout(const float* __restrict__ s2, const float* __restrict__ W1,
                          const float* __restrict__ W2, float* __restrict__ out) {
  int n = blockIdx.x * blockDim.x + threadIdx.x;
  if (n >= NN) return;
  float hbuf[13];
  const float i32 = 0.17677669529663687f;  // 1/sqrt(32)
#pragma unroll
  for (int j = 0; j < 13; j++) {
    float a = 0.f;
#pragma unroll 8
    for (int u = 0; u < 32; u++) a += s2[n*32 + u] * W1[u*13 + j];
    hbuf[j] = siluf(a * i32);
  }
  const float i13 = 0.2773500981126146f;   // 1/sqrt(13)
#pragma unroll
  for (int j2 = 0; j2 < 13; j2++) {
    float a = 0.f;
#pragma unroll
    for (int j = 0; j < 13; j++) a += hbuf[j] * W2[j*13 + j2];
    out[n*13 + j2] = a * i13;
  }
}

extern "C" void kernel_launch(void* const* d_in, const int* in_sizes, int n_in,
                              void* d_out, int out_size, void* d_ws, size_t ws_size,
                              hipStream_t stream) {
  (void)in_sizes; (void)n_in; (void)out_size; (void)ws_size;
  const float* coords = (const float*)d_in[0];
  const int*   atype  = (const int*)d_in[1];
  const int*   eidx   = (const int*)d_in[2];
  const float* emb    = (const float*)d_in[3];
  const float* ipW0 = (const float*)d_in[4];
  const float* ipb0 = (const float*)d_in[5];
  const float* ipW1 = (const float*)d_in[6];
  const float* ipb1 = (const float*)d_in[7];
  const float* lyW0 = (const float*)d_in[8];
  const float* lyb0 = (const float*)d_in[9];
  const float* lyW1 = (const float*)d_in[10];
  const float* lyb1 = (const float*)d_in[11];
  const float* lyWs = (const float*)d_in[12];
  const float* lyWv = (const float*)d_in[13];
  const float* etW0 = (const float*)d_in[14];
  const float* etb0 = (const float*)d_in[15];
  const float* etW1 = (const float*)d_in[16];
  const float* etb1 = (const float*)d_in[17];
  const float* noW1 = (const float*)d_in[18];
  const float* noW2 = (const float*)d_in[19];

  float* ws = (float*)d_ws;
  float* sh    = ws;                  // E*3  = 120000
  float* h_ip  = ws + 120000;         // E*8  = 320000
  float* h_ly  = ws + 440000;         // E*8
  float* h_et  = ws + 760000;         // E*8
  float* s0    = ws + 1080000;        // N*32
  float* s1    = ws + 1240000;        // N*32
  float* v1    = ws + 1400000;        // N*96
  float* s2    = ws + 1880000;        // N*32
  float* v2    = ws + 2040000;        // N*96
  float* cnt   = ws + 2520000;        // N          -- zeroed region start
  float* accS  = ws + 2525000;        // N*32
  float* accV  = ws + 2685000;        // N*96
  float* acc2S = ws + 3165000;        // N*32
  float* acc2V = ws + 3325000;        // N*96       -- ends at 3805000 floats

  float* outE = (float*)d_out;            // E*5
  float* outN = (float*)d_out + NE*5;     // N*13

  hipMemsetAsync(cnt, 0, (size_t)1285000 * sizeof(float), stream);
  k_embed<<<(NN*32 + 255)/256, 256, 0, stream>>>(atype, emb, s0);
  k_geom<<<(NE + 255)/256, 256, 0, stream>>>(coords, eidx, ipW0, ipb0, lyW0, lyb0,
                                             etW0, etb0, sh, h_ip, h_ly, h_et, cnt);
  // init conv: FCTP(32x0e, 0e+1o -> 32x0e+32x1o), c = 1/sqrt(32)
  k_sconv<<<1024, 256, 0, stream>>>(h_ip, sh, s0, eidx, ipW1, ipb1, 2048,
                                    0.17677669529663687f, accS, accV);
  k_n1<<<(NN*32 + 255)/256, 256, 0, stream>>>(cnt, accS, accV, s1, v1);
  // hidden conv paths {0,1} (scalar-driven), c = 1/sqrt(64)
  k_sconv<<<1024, 256, 0, stream>>>(h_ly, sh, s1, eidx, lyW1, lyb1, 4096,
                                    0.125f, acc2S, acc2V);
  // hidden conv paths {2,3} (vector-driven)
  k_vconv<<<1024, 256, 0, stream>>>(h_ly, sh, v1, eidx, lyW1, lyb1, acc2S, acc2V);
  k_n2<<<(NN*32 + 255)/256, 256, 0, stream>>>(cnt, acc2S, acc2V, s1, v1, lyWs, lyWv, s2, v2);
  k_e3<<<1024, 256, 0, stream>>>(h_et, sh, s2, v2, eidx, etW1, etb1, outE);
  k_nodeout<<<(NN + 255)/256, 256, 0, stream>>>(s2, noW1, noW2, outN);
}

// Round 4
// 315.667 us; speedup vs baseline: 1.2361x; 1.2361x over previous
//
#include <hip/hip_runtime.h>

#define NN 5000
#define NE 40000

typedef unsigned int u32;
typedef unsigned short u16;

__device__ __forceinline__ float siluf(float x) { return x / (1.f + __expf(-x)); }

__device__ __forceinline__ u32 f2bf_u(float f) {
  u32 x = __float_as_uint(f);
  return (x + 0x7FFFu + ((x >> 16) & 1u)) >> 16;  // RNE
}
__device__ __forceinline__ u16 f2bf(float f) { return (u16)f2bf_u(f); }
__device__ __forceinline__ float bf2f(u16 v) { return __uint_as_float(((u32)v) << 16); }
__device__ __forceinline__ u32 packbf2(float lo, float hi) {
  return f2bf_u(lo) | (f2bf_u(hi) << 16);
}
__device__ __forceinline__ void unpack8(uint4 q, float* f) {
  f[0] = __uint_as_float(q.x << 16); f[1] = __uint_as_float(q.x & 0xFFFF0000u);
  f[2] = __uint_as_float(q.y << 16); f[3] = __uint_as_float(q.y & 0xFFFF0000u);
  f[4] = __uint_as_float(q.z << 16); f[5] = __uint_as_float(q.z & 0xFFFF0000u);
  f[6] = __uint_as_float(q.w << 16); f[7] = __uint_as_float(q.w & 0xFFFF0000u);
}
__device__ __forceinline__ float dot8f(const float* h, const float* w, float init) {
  float a = init;
#pragma unroll
  for (int k = 0; k < 8; k++) a = fmaf(h[k], w[k], a);
  return a;
}
__device__ __forceinline__ void mlp8(const float* ea, const float* __restrict__ W0,
                                     const float* __restrict__ b0, float* h) {
#pragma unroll
  for (int j = 0; j < 8; j++) {
    float a = b0[j];
#pragma unroll
    for (int i = 0; i < 8; i++) a += ea[i] * W0[i*8 + j];
    h[j] = siluf(a);
  }
}

// ---- geometry + all three radial-MLP hidden activations ----
__global__ void k_geom(const float* __restrict__ coords, const int* __restrict__ eidx,
                       const float* __restrict__ ipW0, const float* __restrict__ ipb0,
                       const float* __restrict__ lyW0, const float* __restrict__ lyb0,
                       const float* __restrict__ etW0, const float* __restrict__ etb0,
                       float* __restrict__ sh, float* __restrict__ h_ip,
                       float* __restrict__ h_ly, float* __restrict__ h_et) {
  int e = blockIdx.x * blockDim.x + threadIdx.x;
  if (e >= NE) return;
  int s = eidx[e], d = eidx[NE + e];
  float vx = coords[d*3+0] - coords[s*3+0];
  float vy = coords[d*3+1] - coords[s*3+1];
  float vz = coords[d*3+2] - coords[s*3+2];
  float dist = sqrtf(vx*vx + vy*vy + vz*vz + 1e-12f);
  float inv = 1.f / dist;
  const float SQ3 = 1.7320508075688772f;
  sh[e*3+0] = SQ3 * vy * inv;   // e3nn (y,z,x) order
  sh[e*3+1] = SQ3 * vz * inv;
  sh[e*3+2] = SQ3 * vx * inv;
  float ea[8];
  const float step = 5.f / 9.f;
#pragma unroll
  for (int j = 0; j < 8; j++) {
    float diff = (dist - step * (float)(j+1)) * (9.f / 5.f);
    ea[j] = __expf(-diff*diff) * (1.f / 1.12f);
  }
  float h[8];
  mlp8(ea, ipW0, ipb0, h);
#pragma unroll
  for (int j = 0; j < 8; j++) h_ip[e*8+j] = h[j];
  mlp8(ea, lyW0, lyb0, h);
#pragma unroll
  for (int j = 0; j < 8; j++) h_ly[e*8+j] = h[j];
  mlp8(ea, etW0, etb0, h);
#pragma unroll
  for (int j = 0; j < 8; j++) h_et[e*8+j] = h[j];
}

// ---- bucket fill: perm[dst*64 + ticket] = e; cur[dst] ends as degree ----
__global__ void k_fill(const int* __restrict__ eidx, int* __restrict__ cur,
                       int* __restrict__ perm) {
  int e = blockIdx.x * blockDim.x + threadIdx.x;
  if (e >= NE) return;
  int d = eidx[NE + e];
  int t = atomicAdd(&cur[d], 1);
  if (t < 64) perm[d*64 + t] = e;
}

// ---- embedding gather ----
__global__ void k_embed(const int* __restrict__ at, const float* __restrict__ emb,
                        float* __restrict__ s0) {
  int t = blockIdx.x * blockDim.x + threadIdx.x;
  if (t >= NN*32) return;
  s0[t] = emb[at[t >> 5]*32 + (t & 31)];
}

// ---- scalar-driven conv (init TP, or hidden paths {0,1}) -> bf16 message records ----
// msg layout per edge: [0:32) scalar-out channels, [32+i*32+w] = v component i, channel w.
__global__ __launch_bounds__(256, 4) void k_sconv(
    const float* __restrict__ hE, const float* __restrict__ sh,
    const float* __restrict__ sIn, const int* __restrict__ eidx,
    const float* __restrict__ W1, const float* __restrict__ b1,
    int ldw, float cscale, u16* __restrict__ msg) {
  __shared__ uint4 Wp[2048];   // [path*1024 + j], 8 bf16 k-values per entry
  __shared__ float2 Bp[1024];  // (b_path0[j], b_path1[j])
  for (int t = threadIdx.x; t < 2048; t += 256) {
    const float* s = W1 + t;
    uint4 q;
    q.x = packbf2(s[0],       s[ldw]);
    q.y = packbf2(s[2*ldw],   s[3*ldw]);
    q.z = packbf2(s[4*ldw],   s[5*ldw]);
    q.w = packbf2(s[6*ldw],   s[7*ldw]);
    Wp[t] = q;
  }
  for (int t = threadIdx.x; t < 1024; t += 256)
    Bp[t] = make_float2(b1[t], b1[1024 + t]);
  __syncthreads();
  const int g = threadIdx.x >> 5, tw = threadIdx.x & 31;
  for (int p = blockIdx.x*8 + g; p*4 < NE; p += gridDim.x*8) {
    int e0 = p*4;
    float h[4][8];
#pragma unroll
    for (int a = 0; a < 4; a++) {
      float4 qa = *(const float4*)&hE[(e0+a)*8];
      float4 qb = *(const float4*)&hE[(e0+a)*8+4];
      h[a][0]=qa.x; h[a][1]=qa.y; h[a][2]=qa.z; h[a][3]=qa.w;
      h[a][4]=qb.x; h[a][5]=qb.y; h[a][6]=qb.z; h[a][7]=qb.w;
    }
    float x[4];
#pragma unroll
    for (int a = 0; a < 4; a++) x[a] = sIn[eidx[e0+a]*32 + tw];
    float as[4] = {0,0,0,0}, av[4] = {0,0,0,0};
#pragma unroll 8
    for (int u = 0; u < 32; u++) {
      int j = u*32 + tw;
      uint4 qs = Wp[j];
      uint4 qv = Wp[1024 + j];
      float2 bb = Bp[j];
      float fs[8], fv[8];
      unpack8(qs, fs);
      unpack8(qv, fv);
#pragma unroll
      for (int a = 0; a < 4; a++) {
        float su = __shfl(x[a], u, 32);
        as[a] = fmaf(su, dot8f(h[a], fs, bb.x), as[a]);
        av[a] = fmaf(su, dot8f(h[a], fv, bb.y), av[a]);
      }
    }
#pragma unroll
    for (int a = 0; a < 4; a++) {
      int e = e0 + a;
      u16* mp = msg + (size_t)e*128;
      mp[tw] = f2bf(cscale*as[a]);
      float m = cscale*av[a];
      mp[32 + 0*32 + tw] = f2bf(m*sh[e*3+0]);
      mp[32 + 1*32 + tw] = f2bf(m*sh[e*3+1]);
      mp[32 + 2*32 + tw] = f2bf(m*sh[e*3+2]);
    }
  }
}

// ---- vector-driven conv (hidden paths {2,3}) -> bf16 message records ----
__global__ __launch_bounds__(256, 4) void k_vconv(
    const float* __restrict__ hE, const float* __restrict__ sh,
    const float* __restrict__ vIn, const int* __restrict__ eidx,
    const float* __restrict__ W1, const float* __restrict__ b1,
    u16* __restrict__ msg) {
  __shared__ uint4 Wp[2048];
  __shared__ float2 Bp[1024];
  for (int t = threadIdx.x; t < 2048; t += 256) {
    const float* s = W1 + 2048 + t;   // paths {2,3}: cols [2048, 4096)
    uint4 q;
    q.x = packbf2(s[0],        s[4096]);
    q.y = packbf2(s[2*4096],   s[3*4096]);
    q.z = packbf2(s[4*4096],   s[5*4096]);
    q.w = packbf2(s[6*4096],   s[7*4096]);
    Wp[t] = q;
  }
  for (int t = threadIdx.x; t < 1024; t += 256)
    Bp[t] = make_float2(b1[2048 + t], b1[3072 + t]);
  __syncthreads();
  const int g = threadIdx.x >> 5, tw = threadIdx.x & 31;
  const float c = 0.125f;                 // 1/sqrt(64)
  const float is3 = 0.5773502691896258f;  // 1/sqrt(3)
  for (int p = blockIdx.x*8 + g; p*4 < NE; p += gridDim.x*8) {
    int e0 = p*4;
    float h[4][8];
#pragma unroll
    for (int a = 0; a < 4; a++) {
      float4 qa = *(const float4*)&hE[(e0+a)*8];
      float4 qb = *(const float4*)&hE[(e0+a)*8+4];
      h[a][0]=qa.x; h[a][1]=qa.y; h[a][2]=qa.z; h[a][3]=qa.w;
      h[a][4]=qb.x; h[a][5]=qb.y; h[a][6]=qb.z; h[a][7]=qb.w;
    }
    float vx[4], vy[4], vz[4], dd[4];
#pragma unroll
    for (int a = 0; a < 4; a++) {
      int sa = eidx[e0+a];
      vx[a] = vIn[sa*96 + tw*3 + 0];
      vy[a] = vIn[sa*96 + tw*3 + 1];
      vz[a] = vIn[sa*96 + tw*3 + 2];
      dd[a] = (vx[a]*sh[(e0+a)*3+0] + vy[a]*sh[(e0+a)*3+1] + vz[a]*sh[(e0+a)*3+2]) * is3;
    }
    float tvx[4] = {0,0,0,0}, tvy[4] = {0,0,0,0}, tvz[4] = {0,0,0,0}, ts[4] = {0,0,0,0};
#pragma unroll 8
    for (int u = 0; u < 32; u++) {
      int j = u*32 + tw;
      uint4 q2 = Wp[j];
      uint4 q3 = Wp[1024 + j];
      float2 bb = Bp[j];
      float f2[8], f3[8];
      unpack8(q2, f2);
      unpack8(q3, f3);
#pragma unroll
      for (int a = 0; a < 4; a++) {
        float w2 = dot8f(h[a], f2, bb.x);
        float w3 = dot8f(h[a], f3, bb.y);
        float ux = __shfl(vx[a], u, 32);
        float uy = __shfl(vy[a], u, 32);
        float uz = __shfl(vz[a], u, 32);
        float du = __shfl(dd[a], u, 32);
        tvx[a] = fmaf(ux, w2, tvx[a]);
        tvy[a] = fmaf(uy, w2, tvy[a]);
        tvz[a] = fmaf(uz, w2, tvz[a]);
        ts[a]  = fmaf(du, w3, ts[a]);
      }
    }
#pragma unroll
    for (int a = 0; a < 4; a++) {
      int e = e0 + a;
      u16* mp = msg + (size_t)e*128;
      mp[tw] = f2bf(c*ts[a]);
      mp[32 + 0*32 + tw] = f2bf(c*tvx[a]);
      mp[32 + 1*32 + tw] = f2bf(c*tvy[a]);
      mp[32 + 2*32 + tw] = f2bf(c*tvz[a]);
    }
  }
}

// ---- gather + mean (conv1) ----
__global__ void k_gather1(const u16* __restrict__ msg, const int* __restrict__ perm,
                          const int* __restrict__ cur, float* __restrict__ s1,
                          float* __restrict__ v1) {
  int t = blockIdx.x * blockDim.x + threadIdx.x;
  int n = t >> 7, c = t & 127;
  if (n >= NN) return;
  int deg = min(cur[n], 64);
  float acc = 0.f;
  for (int j = 0; j < deg; j++) {
    int e = perm[n*64 + j];
    acc += bf2f(msg[(size_t)e*128 + c]);
  }
  acc /= (float)max(deg, 1);
  if (c < 32) s1[n*32 + c] = acc;
  else { int i = (c-32) >> 5, w = (c-32) & 31; v1[n*96 + w*3 + i] = acc; }
}

// ---- gather + mean (conv2, two msg buffers) + linear self-interaction ----
__global__ void k_gather2(const u16* __restrict__ msgA, const u16* __restrict__ msgB,
                          const int* __restrict__ perm, const int* __restrict__ cur,
                          const float* __restrict__ s1, const float* __restrict__ v1,
                          const float* __restrict__ Ws, const float* __restrict__ Wv,
                          float* __restrict__ s2, float* __restrict__ v2) {
  int t = blockIdx.x * blockDim.x + threadIdx.x;
  int n = t >> 7, c = t & 127;
  if (n >= NN) return;
  int deg = min(cur[n], 64);
  float acc = 0.f;
  for (int j = 0; j < deg; j++) {
    int e = perm[n*64 + j];
    acc += bf2f(msgA[(size_t)e*128 + c]) + bf2f(msgB[(size_t)e*128 + c]);
  }
  acc /= (float)max(deg, 1);
  const float lc = 0.17677669529663687f;  // 1/sqrt(32)
  if (c < 32) {
    float ss = 0.f;
#pragma unroll 8
    for (int u = 0; u < 32; u++) ss += s1[n*32 + u] * Ws[u*32 + c];
    s2[n*32 + c] = acc + lc*ss;
  } else {
    int i = (c-32) >> 5, w = (c-32) & 31;
    float sv = 0.f;
#pragma unroll 8
    for (int u = 0; u < 32; u++) sv += v1[n*96 + u*3 + i] * Wv[u*32 + w];
    v2[n*96 + w*3 + i] = acc + lc*sv;
  }
}

// ---- edge output TP -> 5x0e; lanes = u, 4 edges per group pass ----
__global__ __launch_bounds__(256, 4) void k_e3(
    const float* __restrict__ hE, const float* __restrict__ sh,
    const float* __restrict__ s2, const float* __restrict__ v2,
    const int* __restrict__ eidx,
    const float* __restrict__ W1, const float* __restrict__ b1,
    float* __restrict__ out) {
  __shared__ uint4 WQ[640];   // [(w*4+p)*32 + u] : 8 bf16 k-values
  __shared__ float BQ[640];
  for (int t = threadIdx.x; t < 640; t += 256) {
    int u = t & 31, wp = t >> 5, p2 = wp & 3, w = wp >> 2;
    int col = p2*160 + u*5 + w;
    const float* s = W1 + col;
    uint4 q;
    q.x = packbf2(s[0],      s[640]);
    q.y = packbf2(s[1280],   s[1920]);
    q.z = packbf2(s[2560],   s[3200]);
    q.w = packbf2(s[3840],   s[4480]);
    WQ[t] = q;
    BQ[t] = b1[col];
  }
  __syncthreads();
  const int g = threadIdx.x >> 5, tw = threadIdx.x & 31;
  const float c = 0.08838834764831845f;   // 1/sqrt(128)
  const float is3 = 0.5773502691896258f;
  for (int p = blockIdx.x*8 + g; p*4 < NE; p += gridDim.x*8) {
    int e0 = p*4;
    float h[4][8];
    float xs[4], xd[4], ys[4], yd[4];
#pragma unroll
    for (int a = 0; a < 4; a++) {
      float4 qa = *(const float4*)&hE[(e0+a)*8];
      float4 qb = *(const float4*)&hE[(e0+a)*8+4];
      h[a][0]=qa.x; h[a][1]=qa.y; h[a][2]=qa.z; h[a][3]=qa.w;
      h[a][4]=qb.x; h[a][5]=qb.y; h[a][6]=qb.z; h[a][7]=qb.w;
      int sA = eidx[e0+a], dA = eidx[NE+e0+a];
      float s0v = sh[(e0+a)*3+0], s1v = sh[(e0+a)*3+1], s2v = sh[(e0+a)*3+2];
      xs[a] = s2[sA*32 + tw];
      xd[a] = (v2[sA*96+tw*3+0]*s0v + v2[sA*96+tw*3+1]*s1v + v2[sA*96+tw*3+2]*s2v) * is3;
      ys[a] = s2[dA*32 + tw];
      yd[a] = (v2[dA*96+tw*3+0]*s0v + v2[dA*96+tw*3+1]*s1v + v2[dA*96+tw*3+2]*s2v) * is3;
    }
    float part[4][5];
#pragma unroll
    for (int w = 0; w < 5; w++) {
      float f0[8], f1[8], f2[8], f3[8];
      unpack8(WQ[(w*4+0)*32 + tw], f0);
      unpack8(WQ[(w*4+1)*32 + tw], f1);
      unpack8(WQ[(w*4+2)*32 + tw], f2);
      unpack8(WQ[(w*4+3)*32 + tw], f3);
      float b0v = BQ[(w*4+0)*32 + tw];
      float b1v = BQ[(w*4+1)*32 + tw];
      float b2v = BQ[(w*4+2)*32 + tw];
      float b3v = BQ[(w*4+3)*32 + tw];
#pragma unroll
      for (int a = 0; a < 4; a++) {
        float w0 = dot8f(h[a], f0, b0v);
        float w1 = dot8f(h[a], f1, b1v);
        float w2 = dot8f(h[a], f2, b2v);
        float w3 = dot8f(h[a], f3, b3v);
        part[a][w] = xs[a]*w0 + xd[a]*w1 + ys[a]*w2 + yd[a]*w3;
      }
    }
#pragma unroll
    for (int off = 16; off > 0; off >>= 1)
#pragma unroll
      for (int a = 0; a < 4; a++)
#pragma unroll
        for (int w = 0; w < 5; w++)
          part[a][w] += __shfl_xor(part[a][w], off, 32);
    float outv = 0.f;
#pragma unroll
    for (int a = 0; a < 4; a++)
#pragma unroll
      for (int w = 0; w < 5; w++)
        if (tw == a*5 + w) outv = part[a][w];
    if (tw < 20) out[e0*5 + tw] = c * outv;
  }
}

// ---- node output MLP ----
__global__ void k_nodeout(const float* __restrict__ s2, const float* __restrict__ W1,
                          const float* __restrict__ W2, float* __restrict__ out) {
  int n = blockIdx.x * blockDim.x + threadIdx.x;
  if (n >= NN) return;
  float hbuf[13];
  const float i32 = 0.17677669529663687f;  // 1/sqrt(32)
#pragma unroll
  for (int j = 0; j < 13; j++) {
    float a = 0.f;
#pragma unroll 8
    for (int u = 0; u < 32; u++) a += s2[n*32 + u] * W1[u*13 + j];
    hbuf[j] = siluf(a * i32);
  }
  const float i13 = 0.2773500981126146f;   // 1/sqrt(13)
#pragma unroll
  for (int j2 = 0; j2 < 13; j2++) {
    float a = 0.f;
#pragma unroll
    for (int j = 0; j < 13; j++) a += hbuf[j] * W2[j*13 + j2];
    out[n*13 + j2] = a * i13;
  }
}

extern "C" void kernel_launch(void* const* d_in, const int* in_sizes, int n_in,
                              void* d_out, int out_size, void* d_ws, size_t ws_size,
                              hipStream_t stream) {
  (void)in_sizes; (void)n_in; (void)out_size; (void)ws_size;
  const float* coords = (const float*)d_in[0];
  const int*   atype  = (const int*)d_in[1];
  const int*   eidx   = (const int*)d_in[2];
  const float* emb    = (const float*)d_in[3];
  const float* ipW0 = (const float*)d_in[4];
  const float* ipb0 = (const float*)d_in[5];
  const float* ipW1 = (const float*)d_in[6];
  const float* ipb1 = (const float*)d_in[7];
  const float* lyW0 = (const float*)d_in[8];
  const float* lyb0 = (const float*)d_in[9];
  const float* lyW1 = (const float*)d_in[10];
  const float* lyb1 = (const float*)d_in[11];
  const float* lyWs = (const float*)d_in[12];
  const float* lyWv = (const float*)d_in[13];
  const float* etW0 = (const float*)d_in[14];
  const float* etb0 = (const float*)d_in[15];
  const float* etW1 = (const float*)d_in[16];
  const float* etb1 = (const float*)d_in[17];
  const float* noW1 = (const float*)d_in[18];
  const float* noW2 = (const float*)d_in[19];

  float* ws = (float*)d_ws;
  float* sh    = ws;                  // E*3  = 120000
  float* h_ip  = ws + 120000;         // E*8
  float* h_ly  = ws + 440000;         // E*8
  float* h_et  = ws + 760000;         // E*8
  float* s0    = ws + 1080000;        // N*32
  float* s1    = ws + 1240000;        // N*32
  float* v1    = ws + 1400000;        // N*96
  float* s2    = ws + 1880000;        // N*32
  float* v2    = ws + 2040000;        // N*96  -> ends 2520000
  int*   cur   = (int*)(ws + 2520000);   // N ints (zeroed)
  int*   perm  = (int*)(ws + 2525000);   // N*64 ints -> ends 2845000
  u16*   msgA  = (u16*)(ws + 2845000);   // E*128 bf16 = 2560000 floats
  u16*   msgB  = (u16*)(ws + 5405000);   // E*128 bf16 -> ends 7965000 floats (31.9 MB)

  float* outE = (float*)d_out;            // E*5
  float* outN = (float*)d_out + NE*5;     // N*13

  hipMemsetAsync(cur, 0, (size_t)NN * sizeof(int), stream);
  k_embed<<<(NN*32 + 255)/256, 256, 0, stream>>>(atype, emb, s0);
  k_geom<<<(NE + 255)/256, 256, 0, stream>>>(coords, eidx, ipW0, ipb0, lyW0, lyb0,
                                             etW0, etb0, sh, h_ip, h_ly, h_et);
  k_fill<<<(NE + 255)/256, 256, 0, stream>>>(eidx, cur, perm);
  // init conv: FCTP(32x0e, 0e+1o -> 32x0e+32x1o), c = 1/sqrt(32)
  k_sconv<<<1024, 256, 0, stream>>>(h_ip, sh, s0, eidx, ipW1, ipb1, 2048,
                                    0.17677669529663687f, msgA);
  k_gather1<<<(NN*128 + 255)/256, 256, 0, stream>>>(msgA, perm, cur, s1, v1);
  // hidden conv paths {0,1} (scalar-driven), c = 1/sqrt(64)
  k_sconv<<<1024, 256, 0, stream>>>(h_ly, sh, s1, eidx, lyW1, lyb1, 4096,
                                    0.125f, msgA);
  // hidden conv paths {2,3} (vector-driven)
  k_vconv<<<1024, 256, 0, stream>>>(h_ly, sh, v1, eidx, lyW1, lyb1, msgB);
  k_gather2<<<(NN*128 + 255)/256, 256, 0, stream>>>(msgA, msgB, perm, cur, s1, v1,
                                                    lyWs, lyWv, s2, v2);
  k_e3<<<1024, 256, 0, stream>>>(h_et, sh, s2, v2, eidx, etW1, etb1, outE);
  k_nodeout<<<(NN + 255)/256, 256, 0, stream>>>(s2, noW1, noW2, outN);
}

// Round 5
// 280.066 us; speedup vs baseline: 1.3932x; 1.1271x over previous
//
#include <hip/hip_runtime.h>

#define NN 5000
#define NE 40000

typedef unsigned int u32;
typedef unsigned short u16;

__device__ __forceinline__ float siluf(float x) { return x / (1.f + __expf(-x)); }

__device__ __forceinline__ u32 f2bf_u(float f) {
  u32 x = __float_as_uint(f);
  return (x + 0x7FFFu + ((x >> 16) & 1u)) >> 16;  // RNE
}
__device__ __forceinline__ u16 f2bf(float f) { return (u16)f2bf_u(f); }
__device__ __forceinline__ float bf2f(u16 v) { return __uint_as_float(((u32)v) << 16); }
__device__ __forceinline__ u32 packbf2(float lo, float hi) {
  return f2bf_u(lo) | (f2bf_u(hi) << 16);
}
__device__ __forceinline__ void unpack8(uint4 q, float* f) {
  f[0] = __uint_as_float(q.x << 16); f[1] = __uint_as_float(q.x & 0xFFFF0000u);
  f[2] = __uint_as_float(q.y << 16); f[3] = __uint_as_float(q.y & 0xFFFF0000u);
  f[4] = __uint_as_float(q.z << 16); f[5] = __uint_as_float(q.z & 0xFFFF0000u);
  f[6] = __uint_as_float(q.w << 16); f[7] = __uint_as_float(q.w & 0xFFFF0000u);
}
__device__ __forceinline__ float dot8f(const float* h, const float* w, float init) {
  float a = init;
#pragma unroll
  for (int k = 0; k < 8; k++) a = fmaf(h[k], w[k], a);
  return a;
}
__device__ __forceinline__ void mlp8(const float* ea, const float* __restrict__ W0,
                                     const float* __restrict__ b0, float* h) {
#pragma unroll
  for (int j = 0; j < 8; j++) {
    float a = b0[j];
#pragma unroll
    for (int i = 0; i < 8; i++) a += ea[i] * W0[i*8 + j];
    h[j] = siluf(a);
  }
}

// ---- geometry + all three radial-MLP hidden activations ----
__global__ void k_geom(const float* __restrict__ coords, const int* __restrict__ eidx,
                       const float* __restrict__ ipW0, const float* __restrict__ ipb0,
                       const float* __restrict__ lyW0, const float* __restrict__ lyb0,
                       const float* __restrict__ etW0, const float* __restrict__ etb0,
                       float* __restrict__ sh, float* __restrict__ h_ip,
                       float* __restrict__ h_ly, float* __restrict__ h_et) {
  int e = blockIdx.x * blockDim.x + threadIdx.x;
  if (e >= NE) return;
  int s = eidx[e], d = eidx[NE + e];
  float vx = coords[d*3+0] - coords[s*3+0];
  float vy = coords[d*3+1] - coords[s*3+1];
  float vz = coords[d*3+2] - coords[s*3+2];
  float dist = sqrtf(vx*vx + vy*vy + vz*vz + 1e-12f);
  float inv = 1.f / dist;
  const float SQ3 = 1.7320508075688772f;
  sh[e*3+0] = SQ3 * vy * inv;   // e3nn (y,z,x) order
  sh[e*3+1] = SQ3 * vz * inv;
  sh[e*3+2] = SQ3 * vx * inv;
  float ea[8];
  const float step = 5.f / 9.f;
#pragma unroll
  for (int j = 0; j < 8; j++) {
    float diff = (dist - step * (float)(j+1)) * (9.f / 5.f);
    ea[j] = __expf(-diff*diff) * (1.f / 1.12f);
  }
  float h[8];
  mlp8(ea, ipW0, ipb0, h);
#pragma unroll
  for (int j = 0; j < 8; j++) h_ip[e*8+j] = h[j];
  mlp8(ea, lyW0, lyb0, h);
#pragma unroll
  for (int j = 0; j < 8; j++) h_ly[e*8+j] = h[j];
  mlp8(ea, etW0, etb0, h);
#pragma unroll
  for (int j = 0; j < 8; j++) h_et[e*8+j] = h[j];
}

// ---- bucket fill: perm[dst*64 + ticket] = e; cur[dst] ends as degree ----
__global__ void k_fill(const int* __restrict__ eidx, int* __restrict__ cur,
                       int* __restrict__ perm) {
  int e = blockIdx.x * blockDim.x + threadIdx.x;
  if (e >= NE) return;
  int d = eidx[NE + e];
  int t = atomicAdd(&cur[d], 1);
  if (t < 64) perm[d*64 + t] = e;
}

// ---- embedding gather ----
__global__ void k_embed(const int* __restrict__ at, const float* __restrict__ emb,
                        float* __restrict__ s0) {
  int t = blockIdx.x * blockDim.x + threadIdx.x;
  if (t >= NN*32) return;
  s0[t] = emb[at[t >> 5]*32 + (t & 31)];
}

// ---- scalar-driven conv (init TP, or hidden paths {0,1}) -> bf16 message records ----
// msg per edge: [0:32) scalar channels, [32 + i*32 + w] = v component i, channel w.
// 2 edges per 32-lane group pass; no VGPR cap (spill avoidance).
__global__ __launch_bounds__(256) void k_sconv(
    const float* __restrict__ hE, const float* __restrict__ sh,
    const float* __restrict__ sIn, const int* __restrict__ eidx,
    const float* __restrict__ W1, const float* __restrict__ b1,
    int ldw, float cscale, u16* __restrict__ msg) {
  __shared__ uint4 Wp[2048];   // [path*1024 + j], 8 bf16 k-values
  __shared__ float2 Bp[1024];  // (b_path0[j], b_path1[j])
  for (int t = threadIdx.x; t < 2048; t += 256) {
    const float* s = W1 + t;
    uint4 q;
    q.x = packbf2(s[0],       s[ldw]);
    q.y = packbf2(s[2*ldw],   s[3*ldw]);
    q.z = packbf2(s[4*ldw],   s[5*ldw]);
    q.w = packbf2(s[6*ldw],   s[7*ldw]);
    Wp[t] = q;
  }
  for (int t = threadIdx.x; t < 1024; t += 256)
    Bp[t] = make_float2(b1[t], b1[1024 + t]);
  __syncthreads();
  const int g = threadIdx.x >> 5, tw = threadIdx.x & 31;
  for (int p = blockIdx.x*8 + g; p*2 < NE; p += gridDim.x*8) {
    int e0 = p*2, e1 = e0 + 1;
    float h0[8], h1[8];
    {
      float4 qa = *(const float4*)&hE[e0*8];
      float4 qb = *(const float4*)&hE[e0*8+4];
      h0[0]=qa.x; h0[1]=qa.y; h0[2]=qa.z; h0[3]=qa.w;
      h0[4]=qb.x; h0[5]=qb.y; h0[6]=qb.z; h0[7]=qb.w;
      float4 qc = *(const float4*)&hE[e1*8];
      float4 qd = *(const float4*)&hE[e1*8+4];
      h1[0]=qc.x; h1[1]=qc.y; h1[2]=qc.z; h1[3]=qc.w;
      h1[4]=qd.x; h1[5]=qd.y; h1[6]=qd.z; h1[7]=qd.w;
    }
    float x0 = sIn[eidx[e0]*32 + tw];
    float x1 = sIn[eidx[e1]*32 + tw];
    float a0s = 0.f, a0v = 0.f, a1s = 0.f, a1v = 0.f;
#pragma unroll 8
    for (int u = 0; u < 32; u++) {
      int j = u*32 + tw;
      uint4 qs = Wp[j];
      uint4 qv = Wp[1024 + j];
      float2 bb = Bp[j];
      float fs[8], fv[8];
      unpack8(qs, fs);
      unpack8(qv, fv);
      float su0 = __shfl(x0, u, 32), su1 = __shfl(x1, u, 32);
      a0s = fmaf(su0, dot8f(h0, fs, bb.x), a0s);
      a1s = fmaf(su1, dot8f(h1, fs, bb.x), a1s);
      a0v = fmaf(su0, dot8f(h0, fv, bb.y), a0v);
      a1v = fmaf(su1, dot8f(h1, fv, bb.y), a1v);
    }
    u16* mp0 = msg + (size_t)e0*128;
    mp0[tw] = f2bf(cscale*a0s);
    float m0 = cscale*a0v;
    mp0[32 + 0*32 + tw] = f2bf(m0*sh[e0*3+0]);
    mp0[32 + 1*32 + tw] = f2bf(m0*sh[e0*3+1]);
    mp0[32 + 2*32 + tw] = f2bf(m0*sh[e0*3+2]);
    u16* mp1 = msg + (size_t)e1*128;
    mp1[tw] = f2bf(cscale*a1s);
    float m1 = cscale*a1v;
    mp1[32 + 0*32 + tw] = f2bf(m1*sh[e1*3+0]);
    mp1[32 + 1*32 + tw] = f2bf(m1*sh[e1*3+1]);
    mp1[32 + 2*32 + tw] = f2bf(m1*sh[e1*3+2]);
  }
}

// ---- vector-driven conv (hidden paths {2,3}) -> bf16 message records ----
__global__ __launch_bounds__(256) void k_vconv(
    const float* __restrict__ hE, const float* __restrict__ sh,
    const float* __restrict__ vIn, const int* __restrict__ eidx,
    const float* __restrict__ W1, const float* __restrict__ b1,
    u16* __restrict__ msg) {
  __shared__ uint4 Wp[2048];
  __shared__ float2 Bp[1024];
  for (int t = threadIdx.x; t < 2048; t += 256) {
    const float* s = W1 + 2048 + t;   // paths {2,3}: cols [2048, 4096)
    uint4 q;
    q.x = packbf2(s[0],        s[4096]);
    q.y = packbf2(s[2*4096],   s[3*4096]);
    q.z = packbf2(s[4*4096],   s[5*4096]);
    q.w = packbf2(s[6*4096],   s[7*4096]);
    Wp[t] = q;
  }
  for (int t = threadIdx.x; t < 1024; t += 256)
    Bp[t] = make_float2(b1[2048 + t], b1[3072 + t]);
  __syncthreads();
  const int g = threadIdx.x >> 5, tw = threadIdx.x & 31;
  const float c = 0.125f;                 // 1/sqrt(64)
  const float is3 = 0.5773502691896258f;  // 1/sqrt(3)
  for (int p = blockIdx.x*8 + g; p*2 < NE; p += gridDim.x*8) {
    int e0 = p*2, e1 = e0 + 1;
    float h0[8], h1[8];
    {
      float4 qa = *(const float4*)&hE[e0*8];
      float4 qb = *(const float4*)&hE[e0*8+4];
      h0[0]=qa.x; h0[1]=qa.y; h0[2]=qa.z; h0[3]=qa.w;
      h0[4]=qb.x; h0[5]=qb.y; h0[6]=qb.z; h0[7]=qb.w;
      float4 qc = *(const float4*)&hE[e1*8];
      float4 qd = *(const float4*)&hE[e1*8+4];
      h1[0]=qc.x; h1[1]=qc.y; h1[2]=qc.z; h1[3]=qc.w;
      h1[4]=qd.x; h1[5]=qd.y; h1[6]=qd.z; h1[7]=qd.w;
    }
    int sa = eidx[e0], sb = eidx[e1];
    float vax = vIn[sa*96 + tw*3 + 0];
    float vay = vIn[sa*96 + tw*3 + 1];
    float vaz = vIn[sa*96 + tw*3 + 2];
    float vbx = vIn[sb*96 + tw*3 + 0];
    float vby = vIn[sb*96 + tw*3 + 1];
    float vbz = vIn[sb*96 + tw*3 + 2];
    float da = (vax*sh[e0*3+0] + vay*sh[e0*3+1] + vaz*sh[e0*3+2]) * is3;
    float db = (vbx*sh[e1*3+0] + vby*sh[e1*3+1] + vbz*sh[e1*3+2]) * is3;
    float t0x = 0.f, t0y = 0.f, t0z = 0.f, t0s = 0.f;
    float t1x = 0.f, t1y = 0.f, t1z = 0.f, t1s = 0.f;
#pragma unroll 8
    for (int u = 0; u < 32; u++) {
      int j = u*32 + tw;
      uint4 q2 = Wp[j];
      uint4 q3 = Wp[1024 + j];
      float2 bb = Bp[j];
      float f2[8], f3[8];
      unpack8(q2, f2);
      unpack8(q3, f3);
      float w2a = dot8f(h0, f2, bb.x);
      float w2b = dot8f(h1, f2, bb.x);
      float w3a = dot8f(h0, f3, bb.y);
      float w3b = dot8f(h1, f3, bb.y);
      t0x = fmaf(__shfl(vax, u, 32), w2a, t0x);
      t0y = fmaf(__shfl(vay, u, 32), w2a, t0y);
      t0z = fmaf(__shfl(vaz, u, 32), w2a, t0z);
      t0s = fmaf(__shfl(da, u, 32),  w3a, t0s);
      t1x = fmaf(__shfl(vbx, u, 32), w2b, t1x);
      t1y = fmaf(__shfl(vby, u, 32), w2b, t1y);
      t1z = fmaf(__shfl(vbz, u, 32), w2b, t1z);
      t1s = fmaf(__shfl(db, u, 32),  w3b, t1s);
    }
    u16* mp0 = msg + (size_t)e0*128;
    mp0[tw] = f2bf(c*t0s);
    mp0[32 + 0*32 + tw] = f2bf(c*t0x);
    mp0[32 + 1*32 + tw] = f2bf(c*t0y);
    mp0[32 + 2*32 + tw] = f2bf(c*t0z);
    u16* mp1 = msg + (size_t)e1*128;
    mp1[tw] = f2bf(c*t1s);
    mp1[32 + 0*32 + tw] = f2bf(c*t1x);
    mp1[32 + 1*32 + tw] = f2bf(c*t1y);
    mp1[32 + 2*32 + tw] = f2bf(c*t1z);
  }
}

// ---- gather + mean (conv1) ----
__global__ void k_gather1(const u16* __restrict__ msg, const int* __restrict__ perm,
                          const int* __restrict__ cur, float* __restrict__ s1,
                          float* __restrict__ v1) {
  int t = blockIdx.x * blockDim.x + threadIdx.x;
  int n = t >> 7, c = t & 127;
  if (n >= NN) return;
  int deg = min(cur[n], 64);
  float acc = 0.f;
  for (int j = 0; j < deg; j++) {
    int e = perm[n*64 + j];
    acc += bf2f(msg[(size_t)e*128 + c]);
  }
  acc /= (float)max(deg, 1);
  if (c < 32) s1[n*32 + c] = acc;
  else { int i = (c-32) >> 5, w = (c-32) & 31; v1[n*96 + w*3 + i] = acc; }
}

// ---- gather + mean (conv2, two msg buffers) + linear self-interaction ----
__global__ void k_gather2(const u16* __restrict__ msgA, const u16* __restrict__ msgB,
                          const int* __restrict__ perm, const int* __restrict__ cur,
                          const float* __restrict__ s1, const float* __restrict__ v1,
                          const float* __restrict__ Ws, const float* __restrict__ Wv,
                          float* __restrict__ s2, float* __restrict__ v2) {
  int t = blockIdx.x * blockDim.x + threadIdx.x;
  int n = t >> 7, c = t & 127;
  if (n >= NN) return;
  int deg = min(cur[n], 64);
  float acc = 0.f;
  for (int j = 0; j < deg; j++) {
    int e = perm[n*64 + j];
    acc += bf2f(msgA[(size_t)e*128 + c]) + bf2f(msgB[(size_t)e*128 + c]);
  }
  acc /= (float)max(deg, 1);
  const float lc = 0.17677669529663687f;  // 1/sqrt(32)
  if (c < 32) {
    float ss = 0.f;
#pragma unroll 8
    for (int u = 0; u < 32; u++) ss += s1[n*32 + u] * Ws[u*32 + c];
    s2[n*32 + c] = acc + lc*ss;
  } else {
    int i = (c-32) >> 5, w = (c-32) & 31;
    float sv = 0.f;
#pragma unroll 8
    for (int u = 0; u < 32; u++) sv += v1[n*96 + u*3 + i] * Wv[u*32 + w];
    v2[n*96 + w*3 + i] = acc + lc*sv;
  }
}

// ---- edge output TP -> 5x0e; lanes = u, 2 edges per pass, path-major inner loop ----
__global__ __launch_bounds__(256) void k_e3(
    const float* __restrict__ hE, const float* __restrict__ sh,
    const float* __restrict__ s2, const float* __restrict__ v2,
    const int* __restrict__ eidx,
    const float* __restrict__ W1, const float* __restrict__ b1,
    float* __restrict__ out) {
  __shared__ uint4 WQ[640];   // [(p*5+w)*32 + u] : 8 bf16 k-values
  __shared__ float BQ[640];
  for (int t = threadIdx.x; t < 640; t += 256) {
    int u = t & 31, pw = t >> 5, p2 = pw / 5, w = pw - p2*5;
    int col = p2*160 + u*5 + w;
    const float* s = W1 + col;
    uint4 q;
    q.x = packbf2(s[0],      s[640]);
    q.y = packbf2(s[1280],   s[1920]);
    q.z = packbf2(s[2560],   s[3200]);
    q.w = packbf2(s[3840],   s[4480]);
    WQ[t] = q;
    BQ[t] = b1[col];
  }
  __syncthreads();
  const int g = threadIdx.x >> 5, tw = threadIdx.x & 31;
  const float c = 0.08838834764831845f;   // 1/sqrt(128)
  const float is3 = 0.5773502691896258f;
  for (int p = blockIdx.x*8 + g; p*2 < NE; p += gridDim.x*8) {
    int e0 = p*2, e1 = e0 + 1;
    float h0[8], h1[8];
    {
      float4 qa = *(const float4*)&hE[e0*8];
      float4 qb = *(const float4*)&hE[e0*8+4];
      h0[0]=qa.x; h0[1]=qa.y; h0[2]=qa.z; h0[3]=qa.w;
      h0[4]=qb.x; h0[5]=qb.y; h0[6]=qb.z; h0[7]=qb.w;
      float4 qc = *(const float4*)&hE[e1*8];
      float4 qd = *(const float4*)&hE[e1*8+4];
      h1[0]=qc.x; h1[1]=qc.y; h1[2]=qc.z; h1[3]=qc.w;
      h1[4]=qd.x; h1[5]=qd.y; h1[6]=qd.z; h1[7]=qd.w;
    }
    int sA = eidx[e0], dA = eidx[NE+e0];
    int sB = eidx[e1], dB = eidx[NE+e1];
    float sa0 = sh[e0*3+0], sa1 = sh[e0*3+1], sa2 = sh[e0*3+2];
    float sb0 = sh[e1*3+0], sb1 = sh[e1*3+1], sb2 = sh[e1*3+2];
    // coef[p] for edge0: xs, xd, ys, yd
    float c00 = s2[sA*32 + tw];
    float c01 = (v2[sA*96+tw*3+0]*sa0 + v2[sA*96+tw*3+1]*sa1 + v2[sA*96+tw*3+2]*sa2) * is3;
    float c02 = s2[dA*32 + tw];
    float c03 = (v2[dA*96+tw*3+0]*sa0 + v2[dA*96+tw*3+1]*sa1 + v2[dA*96+tw*3+2]*sa2) * is3;
    float c10 = s2[sB*32 + tw];
    float c11 = (v2[sB*96+tw*3+0]*sb0 + v2[sB*96+tw*3+1]*sb1 + v2[sB*96+tw*3+2]*sb2) * is3;
    float c12 = s2[dB*32 + tw];
    float c13 = (v2[dB*96+tw*3+0]*sb0 + v2[dB*96+tw*3+1]*sb1 + v2[dB*96+tw*3+2]*sb2) * is3;
    float part0[5] = {0,0,0,0,0};
    float part1[5] = {0,0,0,0,0};
#pragma unroll
    for (int pp = 0; pp < 4; pp++) {
      float cp0 = (pp==0) ? c00 : (pp==1) ? c01 : (pp==2) ? c02 : c03;
      float cp1 = (pp==0) ? c10 : (pp==1) ? c11 : (pp==2) ? c12 : c13;
#pragma unroll
      for (int w = 0; w < 5; w++) {
        int idx = (pp*5 + w)*32 + tw;
        float f[8];
        unpack8(WQ[idx], f);
        float bv = BQ[idx];
        part0[w] = fmaf(cp0, dot8f(h0, f, bv), part0[w]);
        part1[w] = fmaf(cp1, dot8f(h1, f, bv), part1[w]);
      }
    }
#pragma unroll
    for (int off = 16; off > 0; off >>= 1)
#pragma unroll
      for (int w = 0; w < 5; w++) {
        part0[w] += __shfl_xor(part0[w], off, 32);
        part1[w] += __shfl_xor(part1[w], off, 32);
      }
    float outv = 0.f;
#pragma unroll
    for (int w = 0; w < 5; w++) {
      if (tw == w)     outv = part0[w];
      if (tw == 5 + w) outv = part1[w];
    }
    if (tw < 10) out[e0*5 + tw] = c * outv;
  }
}

// ---- node output MLP ----
__global__ void k_nodeout(const float* __restrict__ s2, const float* __restrict__ W1,
                          const float* __restrict__ W2, float* __restrict__ out) {
  int n = blockIdx.x * blockDim.x + threadIdx.x;
  if (n >= NN) return;
  float hbuf[13];
  const float i32 = 0.17677669529663687f;  // 1/sqrt(32)
#pragma unroll
  for (int j = 0; j < 13; j++) {
    float a = 0.f;
#pragma unroll 8
    for (int u = 0; u < 32; u++) a += s2[n*32 + u] * W1[u*13 + j];
    hbuf[j] = siluf(a * i32);
  }
  const float i13 = 0.2773500981126146f;   // 1/sqrt(13)
#pragma unroll
  for (int j2 = 0; j2 < 13; j2++) {
    float a = 0.f;
#pragma unroll
    for (int j = 0; j < 13; j++) a += hbuf[j] * W2[j*13 + j2];
    out[n*13 + j2] = a * i13;
  }
}

extern "C" void kernel_launch(void* const* d_in, const int* in_sizes, int n_in,
                              void* d_out, int out_size, void* d_ws, size_t ws_size,
                              hipStream_t stream) {
  (void)in_sizes; (void)n_in; (void)out_size; (void)ws_size;
  const float* coords = (const float*)d_in[0];
  const int*   atype  = (const int*)d_in[1];
  const int*   eidx   = (const int*)d_in[2];
  const float* emb    = (const float*)d_in[3];
  const float* ipW0 = (const float*)d_in[4];
  const float* ipb0 = (const float*)d_in[5];
  const float* ipW1 = (const float*)d_in[6];
  const float* ipb1 = (const float*)d_in[7];
  const float* lyW0 = (const float*)d_in[8];
  const float* lyb0 = (const float*)d_in[9];
  const float* lyW1 = (const float*)d_in[10];
  const float* lyb1 = (const float*)d_in[11];
  const float* lyWs = (const float*)d_in[12];
  const float* lyWv = (const float*)d_in[13];
  const float* etW0 = (const float*)d_in[14];
  const float* etb0 = (const float*)d_in[15];
  const float* etW1 = (const float*)d_in[16];
  const float* etb1 = (const float*)d_in[17];
  const float* noW1 = (const float*)d_in[18];
  const float* noW2 = (const float*)d_in[19];

  float* ws = (float*)d_ws;
  float* sh    = ws;                  // E*3  = 120000
  float* h_ip  = ws + 120000;         // E*8
  float* h_ly  = ws + 440000;         // E*8
  float* h_et  = ws + 760000;         // E*8
  float* s0    = ws + 1080000;        // N*32
  float* s1    = ws + 1240000;        // N*32
  float* v1    = ws + 1400000;        // N*96
  float* s2    = ws + 1880000;        // N*32
  float* v2    = ws + 2040000;        // N*96  -> ends 2520000
  int*   cur   = (int*)(ws + 2520000);   // N ints (zeroed)
  int*   perm  = (int*)(ws + 2525000);   // N*64 ints -> ends 2845000
  u16*   msgA  = (u16*)(ws + 2845000);   // E*128 bf16 = 2560000 floats
  u16*   msgB  = (u16*)(ws + 5405000);   // E*128 bf16 -> ends 7965000 floats (31.9 MB)

  float* outE = (float*)d_out;            // E*5
  float* outN = (float*)d_out + NE*5;     // N*13

  hipMemsetAsync(cur, 0, (size_t)NN * sizeof(int), stream);
  k_embed<<<(NN*32 + 255)/256, 256, 0, stream>>>(atype, emb, s0);
  k_geom<<<(NE + 255)/256, 256, 0, stream>>>(coords, eidx, ipW0, ipb0, lyW0, lyb0,
                                             etW0, etb0, sh, h_ip, h_ly, h_et);
  k_fill<<<(NE + 255)/256, 256, 0, stream>>>(eidx, cur, perm);
  // init conv: FCTP(32x0e, 0e+1o -> 32x0e+32x1o), c = 1/sqrt(32)
  k_sconv<<<1024, 256, 0, stream>>>(h_ip, sh, s0, eidx, ipW1, ipb1, 2048,
                                    0.17677669529663687f, msgA);
  k_gather1<<<(NN*128 + 255)/256, 256, 0, stream>>>(msgA, perm, cur, s1, v1);
  // hidden conv paths {0,1} (scalar-driven), c = 1/sqrt(64)
  k_sconv<<<1024, 256, 0, stream>>>(h_ly, sh, s1, eidx, lyW1, lyb1, 4096,
                                    0.125f, msgA);
  // hidden conv paths {2,3} (vector-driven)
  k_vconv<<<1024, 256, 0, stream>>>(h_ly, sh, v1, eidx, lyW1, lyb1, msgB);
  k_gather2<<<(NN*128 + 255)/256, 256, 0, stream>>>(msgA, msgB, perm, cur, s1, v1,
                                                    lyWs, lyWv, s2, v2);
  k_e3<<<1024, 256, 0, stream>>>(h_et, sh, s2, v2, eidx, etW1, etb1, outE);
  k_nodeout<<<(NN + 255)/256, 256, 0, stream>>>(s2, noW1, noW2, outN);
}

// Round 7
// 230.771 us; speedup vs baseline: 1.6908x; 1.2136x over previous
//
#include <hip/hip_runtime.h>

#define NN 5000
#define NE 40000

typedef unsigned int u32;
typedef unsigned short u16;
typedef __attribute__((ext_vector_type(8))) short bf16x8;
typedef __attribute__((ext_vector_type(4))) float f32x4;

union ABfrag { uint4 q; bf16x8 v; u32 u[4]; };

__device__ __forceinline__ float siluf(float x) { return x / (1.f + __expf(-x)); }

__device__ __forceinline__ u32 f2bf_u(float f) {
  u32 x = __float_as_uint(f);
  return (x + 0x7FFFu + ((x >> 16) & 1u)) >> 16;  // RNE
}
__device__ __forceinline__ u16 f2bf(float f) { return (u16)f2bf_u(f); }
__device__ __forceinline__ float bf2f(u16 v) { return __uint_as_float(((u32)v) << 16); }
__device__ __forceinline__ u32 packbf2(float lo, float hi) {
  return f2bf_u(lo) | (f2bf_u(hi) << 16);
}
// fast bf16 pair pack, round-half-away (hi part of compensated split)
__device__ __forceinline__ u32 pk2(float a, float b) {
  return ((__float_as_uint(a) + 0x8000u) >> 16) |
         ((__float_as_uint(b) + 0x8000u) & 0xFFFF0000u);
}
// compensated split: p -> hi (bf16) + lo (bf16 of exact residual)
__device__ __forceinline__ void pksplit8(const float* p, ABfrag& hi, ABfrag& lo) {
#pragma unroll
  for (int j = 0; j < 8; j += 2) {
    u32 h2 = pk2(p[j], p[j+1]);
    hi.u[j >> 1] = h2;
    float h0 = __uint_as_float(h2 << 16);
    float h1 = __uint_as_float(h2 & 0xFFFF0000u);
    lo.u[j >> 1] = pk2(p[j] - h0, p[j+1] - h1);
  }
}
__device__ __forceinline__ void unpack8(uint4 q, float* f) {
  f[0] = __uint_as_float(q.x << 16); f[1] = __uint_as_float(q.x & 0xFFFF0000u);
  f[2] = __uint_as_float(q.y << 16); f[3] = __uint_as_float(q.y & 0xFFFF0000u);
  f[4] = __uint_as_float(q.z << 16); f[5] = __uint_as_float(q.z & 0xFFFF0000u);
  f[6] = __uint_as_float(q.w << 16); f[7] = __uint_as_float(q.w & 0xFFFF0000u);
}
__device__ __forceinline__ float dot8f(const float* h, const float* w, float init) {
  float a = init;
#pragma unroll
  for (int k = 0; k < 8; k++) a = fmaf(h[k], w[k], a);
  return a;
}
__device__ __forceinline__ void mlp8(const float* ea, const float* __restrict__ W0,
                                     const float* __restrict__ b0, float* h) {
#pragma unroll
  for (int j = 0; j < 8; j++) {
    float a = b0[j];
#pragma unroll
    for (int i = 0; i < 8; i++) a += ea[i] * W0[i*8 + j];
    h[j] = siluf(a);
  }
}

// ---- geometry + all three radial-MLP hidden activations ----
__global__ void k_geom(const float* __restrict__ coords, const int* __restrict__ eidx,
                       const float* __restrict__ ipW0, const float* __restrict__ ipb0,
                       const float* __restrict__ lyW0, const float* __restrict__ lyb0,
                       const float* __restrict__ etW0, const float* __restrict__ etb0,
                       float* __restrict__ sh, float* __restrict__ h_ip,
                       float* __restrict__ h_ly, float* __restrict__ h_et) {
  int e = blockIdx.x * blockDim.x + threadIdx.x;
  if (e >= NE) return;
  int s = eidx[e], d = eidx[NE + e];
  float vx = coords[d*3+0] - coords[s*3+0];
  float vy = coords[d*3+1] - coords[s*3+1];
  float vz = coords[d*3+2] - coords[s*3+2];
  float dist = sqrtf(vx*vx + vy*vy + vz*vz + 1e-12f);
  float inv = 1.f / dist;
  const float SQ3 = 1.7320508075688772f;
  sh[e*3+0] = SQ3 * vy * inv;   // e3nn (y,z,x) order
  sh[e*3+1] = SQ3 * vz * inv;
  sh[e*3+2] = SQ3 * vx * inv;
  float ea[8];
  const float step = 5.f / 9.f;
#pragma unroll
  for (int j = 0; j < 8; j++) {
    float diff = (dist - step * (float)(j+1)) * (9.f / 5.f);
    ea[j] = __expf(-diff*diff) * (1.f / 1.12f);
  }
  float h[8];
  mlp8(ea, ipW0, ipb0, h);
#pragma unroll
  for (int j = 0; j < 8; j++) h_ip[e*8+j] = h[j];
  mlp8(ea, lyW0, lyb0, h);
#pragma unroll
  for (int j = 0; j < 8; j++) h_ly[e*8+j] = h[j];
  mlp8(ea, etW0, etb0, h);
#pragma unroll
  for (int j = 0; j < 8; j++) h_et[e*8+j] = h[j];
}

// ---- bucket fill: perm[dst*64 + ticket] = e; cur[dst] ends as degree ----
__global__ void k_fill(const int* __restrict__ eidx, int* __restrict__ cur,
                       int* __restrict__ perm) {
  int e = blockIdx.x * blockDim.x + threadIdx.x;
  if (e >= NE) return;
  int d = eidx[NE + e];
  int t = atomicAdd(&cur[d], 1);
  if (t < 64) perm[d*64 + t] = e;
}

// ---- embedding gather ----
__global__ void k_embed(const int* __restrict__ at, const float* __restrict__ emb,
                        float* __restrict__ s0) {
  int t = blockIdx.x * blockDim.x + threadIdx.x;
  if (t >= NN*32) return;
  s0[t] = emb[at[t >> 5]*32 + (t & 31)];
}

// ---- MFMA conv, scalar-driven pair of paths (conv1 both paths; conv2 paths {0,1}) ----
// GEMM [E x 288] @ [288 x 64]: Z[e] = [h(e) (x) s(src), s(src)]; B rows 256..287 = bias.
// A split hi+lo (compensated bf16) for fp32-grade activation accuracy.
__global__ __launch_bounds__(256) void k_mconv1(
    const float* __restrict__ hE, const float* __restrict__ sh,
    const float* __restrict__ sIn, const int* __restrict__ eidx,
    const float* __restrict__ W1, const float* __restrict__ b1,
    int ldw, float cscale, u16* __restrict__ msg) {
  __shared__ u16 B[64*296];   // B_t[col][k], stride 296 (conflict-free b128 reads)
  {
    int col = threadIdx.x & 63, p = col >> 5, w = col & 31;
    int k0 = (threadIdx.x >> 6) * 72;
    for (int k = k0; k < k0 + 72; k++) {
      float v = (k < 256) ? W1[(k >> 5)*ldw + p*1024 + (k & 31)*32 + w]
                          : b1[p*1024 + (k - 256)*32 + w];
      B[col*296 + k] = f2bf(v);
    }
  }
  __syncthreads();
  int tile = blockIdx.x*4 + (threadIdx.x >> 6);
  if (tile*16 >= NE) return;
  int lane = threadIdx.x & 63;
  int m = lane & 15, q = lane >> 4;
  int e = tile*16 + m;
  int srcn = eidx[e];
  float4 sA = *(const float4*)&sIn[srcn*32 + q*8];
  float4 sB = *(const float4*)&sIn[srcn*32 + q*8 + 4];
  float4 hA = *(const float4*)&hE[e*8];
  float4 hB = *(const float4*)&hE[e*8 + 4];
  float sf[8] = {sA.x,sA.y,sA.z,sA.w,sB.x,sB.y,sB.z,sB.w};
  float hf[8] = {hA.x,hA.y,hA.z,hA.w,hB.x,hB.y,hB.z,hB.w};
  f32x4 acc0 = {0.f,0.f,0.f,0.f}, acc1 = acc0, acc2 = acc0, acc3 = acc0;
#pragma unroll
  for (int ks = 0; ks < 9; ks++) {
    float hs = (ks < 8) ? hf[ks] : 1.f;
    float pr[8];
#pragma unroll
    for (int j = 0; j < 8; j++) pr[j] = hs * sf[j];
    ABfrag ahi, alo;
    pksplit8(pr, ahi, alo);
    int kb = ks*32 + q*8;
    ABfrag b0, b1f, b2, b3;
    b0.q  = *(const uint4*)&B[( 0 + m)*296 + kb];
    b1f.q = *(const uint4*)&B[(16 + m)*296 + kb];
    b2.q  = *(const uint4*)&B[(32 + m)*296 + kb];
    b3.q  = *(const uint4*)&B[(48 + m)*296 + kb];
    acc0 = __builtin_amdgcn_mfma_f32_16x16x32_bf16(ahi.v, b0.v,  acc0, 0, 0, 0);
    acc0 = __builtin_amdgcn_mfma_f32_16x16x32_bf16(alo.v, b0.v,  acc0, 0, 0, 0);
    acc1 = __builtin_amdgcn_mfma_f32_16x16x32_bf16(ahi.v, b1f.v, acc1, 0, 0, 0);
    acc1 = __builtin_amdgcn_mfma_f32_16x16x32_bf16(alo.v, b1f.v, acc1, 0, 0, 0);
    acc2 = __builtin_amdgcn_mfma_f32_16x16x32_bf16(ahi.v, b2.v,  acc2, 0, 0, 0);
    acc2 = __builtin_amdgcn_mfma_f32_16x16x32_bf16(alo.v, b2.v,  acc2, 0, 0, 0);
    acc3 = __builtin_amdgcn_mfma_f32_16x16x32_bf16(ahi.v, b3.v,  acc3, 0, 0, 0);
    acc3 = __builtin_amdgcn_mfma_f32_16x16x32_bf16(alo.v, b3.v,  acc3, 0, 0, 0);
  }
  // C/D: col = lane&15 (= channel n), row = q*4+r (= edge within tile)
#pragma unroll
  for (int r = 0; r < 4; r++) {
    int et = tile*16 + q*4 + r;
    u16* mp = msg + (size_t)et*128;
    mp[m]      = f2bf(cscale*acc0[r]);
    mp[16 + m] = f2bf(cscale*acc1[r]);
    float s0v = sh[et*3+0], s1v = sh[et*3+1], s2v = sh[et*3+2];
    float m0 = cscale*acc2[r], m1 = cscale*acc3[r];
    mp[32 +      m] = f2bf(m0*s0v);
    mp[64 +      m] = f2bf(m0*s1v);
    mp[96 +      m] = f2bf(m0*s2v);
    mp[32 + 16 + m] = f2bf(m1*s0v);
    mp[64 + 16 + m] = f2bf(m1*s1v);
    mp[96 + 16 + m] = f2bf(m1*s2v);
  }
}

// ---- MFMA conv, vector-driven (conv2 paths {2,3}), compensated A split ----
__global__ __launch_bounds__(256) void k_mconv2b(
    const float* __restrict__ hE, const float* __restrict__ sh,
    const float* __restrict__ v1soa, const int* __restrict__ eidx,
    const float* __restrict__ W1, const float* __restrict__ b1,
    u16* __restrict__ msg) {
  __shared__ u16 B[64*296];   // cols 0..31 path2, 32..63 path3
  {
    int col = threadIdx.x & 63;
    int base = (col < 32) ? (2048 + col) : (3072 + (col - 32));
    int k0 = (threadIdx.x >> 6) * 72;
    for (int k = k0; k < k0 + 72; k++) {
      float v = (k < 256) ? W1[(k >> 5)*4096 + base + (k & 31)*32]
                          : b1[base + (k - 256)*32];
      B[col*296 + k] = f2bf(v);
    }
  }
  __syncthreads();
  int tile = blockIdx.x*4 + (threadIdx.x >> 6);
  if (tile*16 >= NE) return;
  const float c = 0.125f, is3 = 0.5773502691896258f;
  int lane = threadIdx.x & 63;
  int m = lane & 15, q = lane >> 4;
  int e = tile*16 + m;
  int srcn = eidx[e];
  float vf[3][8];
#pragma unroll
  for (int i = 0; i < 3; i++) {
    float4 aa = *(const float4*)&v1soa[i*160000 + srcn*32 + q*8];
    float4 bb = *(const float4*)&v1soa[i*160000 + srcn*32 + q*8 + 4];
    vf[i][0]=aa.x; vf[i][1]=aa.y; vf[i][2]=aa.z; vf[i][3]=aa.w;
    vf[i][4]=bb.x; vf[i][5]=bb.y; vf[i][6]=bb.z; vf[i][7]=bb.w;
  }
  float4 hA = *(const float4*)&hE[e*8];
  float4 hB = *(const float4*)&hE[e*8 + 4];
  float hf[8] = {hA.x,hA.y,hA.z,hA.w,hB.x,hB.y,hB.z,hB.w};
  float es0 = sh[e*3+0], es1 = sh[e*3+1], es2 = sh[e*3+2];
  float df[8];
#pragma unroll
  for (int j = 0; j < 8; j++)
    df[j] = (vf[0][j]*es0 + vf[1][j]*es1 + vf[2][j]*es2) * is3;
  f32x4 z = {0.f,0.f,0.f,0.f};
  f32x4 aV00 = z, aV01 = z, aV10 = z, aV11 = z, aV20 = z, aV21 = z, aD0 = z, aD1 = z;
#pragma unroll
  for (int ks = 0; ks < 9; ks++) {
    int kb = ks*32 + q*8;
    ABfrag b0, b1f, b2, b3;
    b0.q  = *(const uint4*)&B[( 0 + m)*296 + kb];
    b1f.q = *(const uint4*)&B[(16 + m)*296 + kb];
    b2.q  = *(const uint4*)&B[(32 + m)*296 + kb];
    b3.q  = *(const uint4*)&B[(48 + m)*296 + kb];
    float hs = (ks < 8) ? hf[ks] : 1.f;
    float pr[8];
    ABfrag hi, lo;
    // component 0
#pragma unroll
    for (int j = 0; j < 8; j++) pr[j] = hs * vf[0][j];
    pksplit8(pr, hi, lo);
    aV00 = __builtin_amdgcn_mfma_f32_16x16x32_bf16(hi.v, b0.v,  aV00, 0, 0, 0);
    aV00 = __builtin_amdgcn_mfma_f32_16x16x32_bf16(lo.v, b0.v,  aV00, 0, 0, 0);
    aV01 = __builtin_amdgcn_mfma_f32_16x16x32_bf16(hi.v, b1f.v, aV01, 0, 0, 0);
    aV01 = __builtin_amdgcn_mfma_f32_16x16x32_bf16(lo.v, b1f.v, aV01, 0, 0, 0);
    // component 1
#pragma unroll
    for (int j = 0; j < 8; j++) pr[j] = hs * vf[1][j];
    pksplit8(pr, hi, lo);
    aV10 = __builtin_amdgcn_mfma_f32_16x16x32_bf16(hi.v, b0.v,  aV10, 0, 0, 0);
    aV10 = __builtin_amdgcn_mfma_f32_16x16x32_bf16(lo.v, b0.v,  aV10, 0, 0, 0);
    aV11 = __builtin_amdgcn_mfma_f32_16x16x32_bf16(hi.v, b1f.v, aV11, 0, 0, 0);
    aV11 = __builtin_amdgcn_mfma_f32_16x16x32_bf16(lo.v, b1f.v, aV11, 0, 0, 0);
    // component 2
#pragma unroll
    for (int j = 0; j < 8; j++) pr[j] = hs * vf[2][j];
    pksplit8(pr, hi, lo);
    aV20 = __builtin_amdgcn_mfma_f32_16x16x32_bf16(hi.v, b0.v,  aV20, 0, 0, 0);
    aV20 = __builtin_amdgcn_mfma_f32_16x16x32_bf16(lo.v, b0.v,  aV20, 0, 0, 0);
    aV21 = __builtin_amdgcn_mfma_f32_16x16x32_bf16(hi.v, b1f.v, aV21, 0, 0, 0);
    aV21 = __builtin_amdgcn_mfma_f32_16x16x32_bf16(lo.v, b1f.v, aV21, 0, 0, 0);
    // dot stream
#pragma unroll
    for (int j = 0; j < 8; j++) pr[j] = hs * df[j];
    pksplit8(pr, hi, lo);
    aD0  = __builtin_amdgcn_mfma_f32_16x16x32_bf16(hi.v, b2.v,  aD0,  0, 0, 0);
    aD0  = __builtin_amdgcn_mfma_f32_16x16x32_bf16(lo.v, b2.v,  aD0,  0, 0, 0);
    aD1  = __builtin_amdgcn_mfma_f32_16x16x32_bf16(hi.v, b3.v,  aD1,  0, 0, 0);
    aD1  = __builtin_amdgcn_mfma_f32_16x16x32_bf16(lo.v, b3.v,  aD1,  0, 0, 0);
  }
#pragma unroll
  for (int r = 0; r < 4; r++) {
    int et = tile*16 + q*4 + r;
    u16* mp = msg + (size_t)et*128;
    mp[m]      = f2bf(c*aD0[r]);
    mp[16 + m] = f2bf(c*aD1[r]);
    mp[32 +      m] = f2bf(c*aV00[r]);
    mp[32 + 16 + m] = f2bf(c*aV01[r]);
    mp[64 +      m] = f2bf(c*aV10[r]);
    mp[64 + 16 + m] = f2bf(c*aV11[r]);
    mp[96 +      m] = f2bf(c*aV20[r]);
    mp[96 + 16 + m] = f2bf(c*aV21[r]);
  }
}

// ---- gather + mean (conv1); v1 written in SoA [i][n][u] ----
__global__ void k_gather1(const u16* __restrict__ msg, const int* __restrict__ perm,
                          const int* __restrict__ cur, float* __restrict__ s1,
                          float* __restrict__ v1soa) {
  int t = blockIdx.x * blockDim.x + threadIdx.x;
  int n = t >> 7, c = t & 127;
  if (n >= NN) return;
  int deg = min(cur[n], 64);
  float acc = 0.f;
  for (int j = 0; j < deg; j++) {
    int e = perm[n*64 + j];
    acc += bf2f(msg[(size_t)e*128 + c]);
  }
  acc /= (float)max(deg, 1);
  if (c < 32) s1[n*32 + c] = acc;
  else { int i = (c-32) >> 5, w = (c-32) & 31; v1soa[i*160000 + n*32 + w] = acc; }
}

// ---- gather + mean (conv2, two msg buffers) + linear self-interaction ----
__global__ void k_gather2(const u16* __restrict__ msgA, const u16* __restrict__ msgB,
                          const int* __restrict__ perm, const int* __restrict__ cur,
                          const float* __restrict__ s1, const float* __restrict__ v1soa,
                          const float* __restrict__ Ws, const float* __restrict__ Wv,
                          float* __restrict__ s2, float* __restrict__ v2) {
  int t = blockIdx.x * blockDim.x + threadIdx.x;
  int n = t >> 7, c = t & 127;
  if (n >= NN) return;
  int deg = min(cur[n], 64);
  float acc = 0.f;
  for (int j = 0; j < deg; j++) {
    int e = perm[n*64 + j];
    acc += bf2f(msgA[(size_t)e*128 + c]) + bf2f(msgB[(size_t)e*128 + c]);
  }
  acc /= (float)max(deg, 1);
  const float lc = 0.17677669529663687f;  // 1/sqrt(32)
  if (c < 32) {
    float ss = 0.f;
#pragma unroll 8
    for (int u = 0; u < 32; u++) ss += s1[n*32 + u] * Ws[u*32 + c];
    s2[n*32 + c] = acc + lc*ss;
  } else {
    int i = (c-32) >> 5, w = (c-32) & 31;
    float sv = 0.f;
#pragma unroll 8
    for (int u = 0; u < 32; u++) sv += v1soa[i*160000 + n*32 + u] * Wv[u*32 + w];
    v2[n*96 + w*3 + i] = acc + lc*sv;
  }
}

// ---- edge output TP -> 5x0e; lanes = u, 2 edges per pass, path-major inner loop ----
__global__ __launch_bounds__(256) void k_e3(
    const float* __restrict__ hE, const float* __restrict__ sh,
    const float* __restrict__ s2, const float* __restrict__ v2,
    const int* __restrict__ eidx,
    const float* __restrict__ W1, const float* __restrict__ b1,
    float* __restrict__ out) {
  __shared__ uint4 WQ[640];   // [(p*5+w)*32 + u] : 8 bf16 k-values
  __shared__ float BQ[640];
  for (int t = threadIdx.x; t < 640; t += 256) {
    int u = t & 31, pw = t >> 5, p2 = pw / 5, w = pw - p2*5;
    int col = p2*160 + u*5 + w;
    const float* s = W1 + col;
    uint4 q;
    q.x = packbf2(s[0],      s[640]);
    q.y = packbf2(s[1280],   s[1920]);
    q.z = packbf2(s[2560],   s[3200]);
    q.w = packbf2(s[3840],   s[4480]);
    WQ[t] = q;
    BQ[t] = b1[col];
  }
  __syncthreads();
  const int g = threadIdx.x >> 5, tw = threadIdx.x & 31;
  const float c = 0.08838834764831845f;   // 1/sqrt(128)
  const float is3 = 0.5773502691896258f;
  for (int p = blockIdx.x*8 + g; p*2 < NE; p += gridDim.x*8) {
    int e0 = p*2, e1 = e0 + 1;
    float h0[8], h1[8];
    {
      float4 qa = *(const float4*)&hE[e0*8];
      float4 qb = *(const float4*)&hE[e0*8+4];
      h0[0]=qa.x; h0[1]=qa.y; h0[2]=qa.z; h0[3]=qa.w;
      h0[4]=qb.x; h0[5]=qb.y; h0[6]=qb.z; h0[7]=qb.w;
      float4 qc = *(const float4*)&hE[e1*8];
      float4 qd = *(const float4*)&hE[e1*8+4];
      h1[0]=qc.x; h1[1]=qc.y; h1[2]=qc.z; h1[3]=qc.w;
      h1[4]=qd.x; h1[5]=qd.y; h1[6]=qd.z; h1[7]=qd.w;
    }
    int sA = eidx[e0], dA = eidx[NE+e0];
    int sB = eidx[e1], dB = eidx[NE+e1];
    float sa0 = sh[e0*3+0], sa1 = sh[e0*3+1], sa2 = sh[e0*3+2];
    float sb0 = sh[e1*3+0], sb1 = sh[e1*3+1], sb2 = sh[e1*3+2];
    float c00 = s2[sA*32 + tw];
    float c01 = (v2[sA*96+tw*3+0]*sa0 + v2[sA*96+tw*3+1]*sa1 + v2[sA*96+tw*3+2]*sa2) * is3;
    float c02 = s2[dA*32 + tw];
    float c03 = (v2[dA*96+tw*3+0]*sa0 + v2[dA*96+tw*3+1]*sa1 + v2[dA*96+tw*3+2]*sa2) * is3;
    float c10 = s2[sB*32 + tw];
    float c11 = (v2[sB*96+tw*3+0]*sb0 + v2[sB*96+tw*3+1]*sb1 + v2[sB*96+tw*3+2]*sb2) * is3;
    float c12 = s2[dB*32 + tw];
    float c13 = (v2[dB*96+tw*3+0]*sb0 + v2[dB*96+tw*3+1]*sb1 + v2[dB*96+tw*3+2]*sb2) * is3;
    float part0[5] = {0,0,0,0,0};
    float part1[5] = {0,0,0,0,0};
#pragma unroll
    for (int pp = 0; pp < 4; pp++) {
      float cp0 = (pp==0) ? c00 : (pp==1) ? c01 : (pp==2) ? c02 : c03;
      float cp1 = (pp==0) ? c10 : (pp==1) ? c11 : (pp==2) ? c12 : c13;
#pragma unroll
      for (int w = 0; w < 5; w++) {
        int idx = (pp*5 + w)*32 + tw;
        float f[8];
        unpack8(WQ[idx], f);
        float bv = BQ[idx];
        part0[w] = fmaf(cp0, dot8f(h0, f, bv), part0[w]);
        part1[w] = fmaf(cp1, dot8f(h1, f, bv), part1[w]);
      }
    }
#pragma unroll
    for (int off = 16; off > 0; off >>= 1)
#pragma unroll
      for (int w = 0; w < 5; w++) {
        part0[w] += __shfl_xor(part0[w], off, 32);
        part1[w] += __shfl_xor(part1[w], off, 32);
      }
    float outv = 0.f;
#pragma unroll
    for (int w = 0; w < 5; w++) {
      if (tw == w)     outv = part0[w];
      if (tw == 5 + w) outv = part1[w];
    }
    if (tw < 10) out[e0*5 + tw] = c * outv;
  }
}

// ---- node output MLP ----
__global__ void k_nodeout(const float* __restrict__ s2, const float* __restrict__ W1,
                          const float* __restrict__ W2, float* __restrict__ out) {
  int n = blockIdx.x * blockDim.x + threadIdx.x;
  if (n >= NN) return;
  float hbuf[13];
  const float i32 = 0.17677669529663687f;  // 1/sqrt(32)
#pragma unroll
  for (int j = 0; j < 13; j++) {
    float a = 0.f;
#pragma unroll 8
    for (int u = 0; u < 32; u++) a += s2[n*32 + u] * W1[u*13 + j];
    hbuf[j] = siluf(a * i32);
  }
  const float i13 = 0.2773500981126146f;   // 1/sqrt(13)
#pragma unroll
  for (int j2 = 0; j2 < 13; j2++) {
    float a = 0.f;
#pragma unroll
    for (int j = 0; j < 13; j++) a += hbuf[j] * W2[j*13 + j2];
    out[n*13 + j2] = a * i13;
  }
}

extern "C" void kernel_launch(void* const* d_in, const int* in_sizes, int n_in,
                              void* d_out, int out_size, void* d_ws, size_t ws_size,
                              hipStream_t stream) {
  (void)in_sizes; (void)n_in; (void)out_size; (void)ws_size;
  const float* coords = (const float*)d_in[0];
  const int*   atype  = (const int*)d_in[1];
  const int*   eidx   = (const int*)d_in[2];
  const float* emb    = (const float*)d_in[3];
  const float* ipW0 = (const float*)d_in[4];
  const float* ipb0 = (const float*)d_in[5];
  const float* ipW1 = (const float*)d_in[6];
  const float* ipb1 = (const float*)d_in[7];
  const float* lyW0 = (const float*)d_in[8];
  const float* lyb0 = (const float*)d_in[9];
  const float* lyW1 = (const float*)d_in[10];
  const float* lyb1 = (const float*)d_in[11];
  const float* lyWs = (const float*)d_in[12];
  const float* lyWv = (const float*)d_in[13];
  const float* etW0 = (const float*)d_in[14];
  const float* etb0 = (const float*)d_in[15];
  const float* etW1 = (const float*)d_in[16];
  const float* etb1 = (const float*)d_in[17];
  const float* noW1 = (const float*)d_in[18];
  const float* noW2 = (const float*)d_in[19];

  float* ws = (float*)d_ws;
  float* sh    = ws;                  // E*3  = 120000
  float* h_ip  = ws + 120000;         // E*8
  float* h_ly  = ws + 440000;         // E*8
  float* h_et  = ws + 760000;         // E*8
  float* s0    = ws + 1080000;        // N*32
  float* s1    = ws + 1240000;        // N*32
  float* v1soa = ws + 1400000;        // 3 planes of 160000 (SoA) = 480000
  float* s2    = ws + 1880000;        // N*32
  float* v2    = ws + 2040000;        // N*96 (AoS)  -> ends 2520000
  int*   cur   = (int*)(ws + 2520000);   // N ints (zeroed)
  int*   perm  = (int*)(ws + 2525000);   // N*64 ints -> ends 2845000
  u16*   msgA  = (u16*)(ws + 2845000);   // E*128 bf16
  u16*   msgB  = (u16*)(ws + 5405000);   // E*128 bf16 -> ends 7965000 floats

  float* outE = (float*)d_out;            // E*5
  float* outN = (float*)d_out + NE*5;     // N*13

  hipMemsetAsync(cur, 0, (size_t)NN * sizeof(int), stream);
  k_embed<<<(NN*32 + 255)/256, 256, 0, stream>>>(atype, emb, s0);
  k_geom<<<(NE + 255)/256, 256, 0, stream>>>(coords, eidx, ipW0, ipb0, lyW0, lyb0,
                                             etW0, etb0, sh, h_ip, h_ly, h_et);
  k_fill<<<(NE + 255)/256, 256, 0, stream>>>(eidx, cur, perm);
  // conv1: FCTP(32x0e, 0e+1o -> 32x0e+32x1o), c = 1/sqrt(32)
  k_mconv1<<<625, 256, 0, stream>>>(h_ip, sh, s0, eidx, ipW1, ipb1, 2048,
                                    0.17677669529663687f, msgA);
  k_gather1<<<(NN*128 + 255)/256, 256, 0, stream>>>(msgA, perm, cur, s1, v1soa);
  // conv2 paths {0,1} (scalar-driven), c = 1/sqrt(64)
  k_mconv1<<<625, 256, 0, stream>>>(h_ly, sh, s1, eidx, lyW1, lyb1, 4096,
                                    0.125f, msgA);
  // conv2 paths {2,3} (vector-driven)
  k_mconv2b<<<625, 256, 0, stream>>>(h_ly, sh, v1soa, eidx, lyW1, lyb1, msgB);
  k_gather2<<<(NN*128 + 255)/256, 256, 0, stream>>>(msgA, msgB, perm, cur, s1, v1soa,
                                                    lyWs, lyWv, s2, v2);
  k_e3<<<1024, 256, 0, stream>>>(h_et, sh, s2, v2, eidx, etW1, etb1, outE);
  k_nodeout<<<(NN + 255)/256, 256, 0, stream>>>(s2, noW1, noW2, outN);
}

// Round 8
// 205.120 us; speedup vs baseline: 1.9022x; 1.1251x over previous
//
#include <hip/hip_runtime.h>

#define NN 5000
#define NE 40000

typedef unsigned int u32;
typedef unsigned short u16;
typedef __attribute__((ext_vector_type(8))) short bf16x8;
typedef __attribute__((ext_vector_type(4))) float f32x4;

union ABfrag { uint4 q; bf16x8 v; u32 u[4]; };

__device__ __forceinline__ float siluf(float x) { return x / (1.f + __expf(-x)); }

__device__ __forceinline__ u32 f2bf_u(float f) {
  u32 x = __float_as_uint(f);
  return (x + 0x7FFFu + ((x >> 16) & 1u)) >> 16;  // RNE
}
__device__ __forceinline__ u16 f2bf(float f) { return (u16)f2bf_u(f); }
__device__ __forceinline__ float bf2f(u16 v) { return __uint_as_float(((u32)v) << 16); }
__device__ __forceinline__ u32 packbf2(float lo, float hi) {
  return f2bf_u(lo) | (f2bf_u(hi) << 16);
}
// fast bf16 pair pack, round-half-away (hi part of compensated split)
__device__ __forceinline__ u32 pk2(float a, float b) {
  return ((__float_as_uint(a) + 0x8000u) >> 16) |
         ((__float_as_uint(b) + 0x8000u) & 0xFFFF0000u);
}
// compensated split: p -> hi (bf16) + lo (bf16 of exact residual)
__device__ __forceinline__ void pksplit8(const float* p, ABfrag& hi, ABfrag& lo) {
#pragma unroll
  for (int j = 0; j < 8; j += 2) {
    u32 h2 = pk2(p[j], p[j+1]);
    hi.u[j >> 1] = h2;
    float h0 = __uint_as_float(h2 << 16);
    float h1 = __uint_as_float(h2 & 0xFFFF0000u);
    lo.u[j >> 1] = pk2(p[j] - h0, p[j+1] - h1);
  }
}
__device__ __forceinline__ void unpack8(uint4 q, float* f) {
  f[0] = __uint_as_float(q.x << 16); f[1] = __uint_as_float(q.x & 0xFFFF0000u);
  f[2] = __uint_as_float(q.y << 16); f[3] = __uint_as_float(q.y & 0xFFFF0000u);
  f[4] = __uint_as_float(q.z << 16); f[5] = __uint_as_float(q.z & 0xFFFF0000u);
  f[6] = __uint_as_float(q.w << 16); f[7] = __uint_as_float(q.w & 0xFFFF0000u);
}
__device__ __forceinline__ float dot8f(const float* h, const float* w, float init) {
  float a = init;
#pragma unroll
  for (int k = 0; k < 8; k++) a = fmaf(h[k], w[k], a);
  return a;
}
__device__ __forceinline__ void mlp8(const float* ea, const float* __restrict__ W0,
                                     const float* __restrict__ b0, float* h) {
#pragma unroll
  for (int j = 0; j < 8; j++) {
    float a = b0[j];
#pragma unroll
    for (int i = 0; i < 8; i++) a += ea[i] * W0[i*8 + j];
    h[j] = siluf(a);
  }
}

// ---- geometry + 3 radial-MLP activations + bucket fill (fused) ----
__global__ void k_geom(const float* __restrict__ coords, const int* __restrict__ eidx,
                       const float* __restrict__ ipW0, const float* __restrict__ ipb0,
                       const float* __restrict__ lyW0, const float* __restrict__ lyb0,
                       const float* __restrict__ etW0, const float* __restrict__ etb0,
                       float* __restrict__ sh, float* __restrict__ h_ip,
                       float* __restrict__ h_ly, float* __restrict__ h_et,
                       int* __restrict__ cur, int* __restrict__ perm) {
  int e = blockIdx.x * blockDim.x + threadIdx.x;
  if (e >= NE) return;
  int s = eidx[e], d = eidx[NE + e];
  float vx = coords[d*3+0] - coords[s*3+0];
  float vy = coords[d*3+1] - coords[s*3+1];
  float vz = coords[d*3+2] - coords[s*3+2];
  float dist = sqrtf(vx*vx + vy*vy + vz*vz + 1e-12f);
  float inv = 1.f / dist;
  const float SQ3 = 1.7320508075688772f;
  sh[e*3+0] = SQ3 * vy * inv;   // e3nn (y,z,x) order
  sh[e*3+1] = SQ3 * vz * inv;
  sh[e*3+2] = SQ3 * vx * inv;
  float ea[8];
  const float step = 5.f / 9.f;
#pragma unroll
  for (int j = 0; j < 8; j++) {
    float diff = (dist - step * (float)(j+1)) * (9.f / 5.f);
    ea[j] = __expf(-diff*diff) * (1.f / 1.12f);
  }
  float h[8];
  mlp8(ea, ipW0, ipb0, h);
#pragma unroll
  for (int j = 0; j < 8; j++) h_ip[e*8+j] = h[j];
  mlp8(ea, lyW0, lyb0, h);
#pragma unroll
  for (int j = 0; j < 8; j++) h_ly[e*8+j] = h[j];
  mlp8(ea, etW0, etb0, h);
#pragma unroll
  for (int j = 0; j < 8; j++) h_et[e*8+j] = h[j];
  int t = atomicAdd(&cur[d], 1);
  if (t < 64) perm[d*64 + t] = e;
}

// ---- MFMA conv, scalar-driven pair of paths (conv1 w/ fused embed; conv2 paths {0,1}) ----
// GEMM [E x 288] @ [288 x 64]: Z[e] = [h(e) (x) s(src), s(src)]; B rows 256..287 = bias.
__global__ __launch_bounds__(256) void k_mconv1(
    const float* __restrict__ hE, const float* __restrict__ sh,
    const float* __restrict__ sIn, const int* __restrict__ atype,
    const int* __restrict__ eidx,
    const float* __restrict__ W1, const float* __restrict__ b1,
    int ldw, float cscale, u16* __restrict__ msg) {
  __shared__ u16 B[64*296];   // B_t[col][k], stride 296 (conflict-free b128 reads)
  {
    int col = threadIdx.x & 63, p = col >> 5, w = col & 31;
    int k0 = (threadIdx.x >> 6) * 72;
    for (int k = k0; k < k0 + 72; k++) {
      float v = (k < 256) ? W1[(k >> 5)*ldw + p*1024 + (k & 31)*32 + w]
                          : b1[p*1024 + (k - 256)*32 + w];
      B[col*296 + k] = f2bf(v);
    }
  }
  __syncthreads();
  int tile = blockIdx.x*4 + (threadIdx.x >> 6);
  if (tile*16 >= NE) return;
  int lane = threadIdx.x & 63;
  int m = lane & 15, q = lane >> 4;
  int e = tile*16 + m;
  int srcn = eidx[e];
  int srow = atype ? atype[srcn] : srcn;   // conv1: gather embedding row directly
  float4 sA = *(const float4*)&sIn[srow*32 + q*8];
  float4 sB = *(const float4*)&sIn[srow*32 + q*8 + 4];
  float4 hA = *(const float4*)&hE[e*8];
  float4 hB = *(const float4*)&hE[e*8 + 4];
  float sf[8] = {sA.x,sA.y,sA.z,sA.w,sB.x,sB.y,sB.z,sB.w};
  float hf[8] = {hA.x,hA.y,hA.z,hA.w,hB.x,hB.y,hB.z,hB.w};
  f32x4 acc0 = {0.f,0.f,0.f,0.f}, acc1 = acc0, acc2 = acc0, acc3 = acc0;
#pragma unroll
  for (int ks = 0; ks < 9; ks++) {
    float hs = (ks < 8) ? hf[ks] : 1.f;
    float pr[8];
#pragma unroll
    for (int j = 0; j < 8; j++) pr[j] = hs * sf[j];
    ABfrag ahi, alo;
    pksplit8(pr, ahi, alo);
    int kb = ks*32 + q*8;
    ABfrag b0, b1f, b2, b3;
    b0.q  = *(const uint4*)&B[( 0 + m)*296 + kb];
    b1f.q = *(const uint4*)&B[(16 + m)*296 + kb];
    b2.q  = *(const uint4*)&B[(32 + m)*296 + kb];
    b3.q  = *(const uint4*)&B[(48 + m)*296 + kb];
    acc0 = __builtin_amdgcn_mfma_f32_16x16x32_bf16(ahi.v, b0.v,  acc0, 0, 0, 0);
    acc0 = __builtin_amdgcn_mfma_f32_16x16x32_bf16(alo.v, b0.v,  acc0, 0, 0, 0);
    acc1 = __builtin_amdgcn_mfma_f32_16x16x32_bf16(ahi.v, b1f.v, acc1, 0, 0, 0);
    acc1 = __builtin_amdgcn_mfma_f32_16x16x32_bf16(alo.v, b1f.v, acc1, 0, 0, 0);
    acc2 = __builtin_amdgcn_mfma_f32_16x16x32_bf16(ahi.v, b2.v,  acc2, 0, 0, 0);
    acc2 = __builtin_amdgcn_mfma_f32_16x16x32_bf16(alo.v, b2.v,  acc2, 0, 0, 0);
    acc3 = __builtin_amdgcn_mfma_f32_16x16x32_bf16(ahi.v, b3.v,  acc3, 0, 0, 0);
    acc3 = __builtin_amdgcn_mfma_f32_16x16x32_bf16(alo.v, b3.v,  acc3, 0, 0, 0);
  }
  // C/D: col = lane&15 (= channel), row = q*4+r (= edge within tile)
#pragma unroll
  for (int r = 0; r < 4; r++) {
    int et = tile*16 + q*4 + r;
    u16* mp = msg + (size_t)et*128;
    mp[m]      = f2bf(cscale*acc0[r]);
    mp[16 + m] = f2bf(cscale*acc1[r]);
    float s0v = sh[et*3+0], s1v = sh[et*3+1], s2v = sh[et*3+2];
    float m0 = cscale*acc2[r], m1 = cscale*acc3[r];
    mp[32 +      m] = f2bf(m0*s0v);
    mp[64 +      m] = f2bf(m0*s1v);
    mp[96 +      m] = f2bf(m0*s2v);
    mp[32 + 16 + m] = f2bf(m1*s0v);
    mp[64 + 16 + m] = f2bf(m1*s1v);
    mp[96 + 16 + m] = f2bf(m1*s2v);
  }
}

// ---- conv2, single dispatch: blocks [0,625) scalar paths {0,1} -> msgA;
//      blocks [625,1250) vector paths {2,3} -> msgB ----
__global__ __launch_bounds__(256) void k_conv2(
    const float* __restrict__ hE, const float* __restrict__ sh,
    const float* __restrict__ s1, const float* __restrict__ v1soa,
    const int* __restrict__ eidx,
    const float* __restrict__ W1, const float* __restrict__ b1,
    u16* __restrict__ msgA, u16* __restrict__ msgB) {
  __shared__ u16 B[64*296];
  const bool scalarHalf = blockIdx.x < 625;
  int blk = scalarHalf ? blockIdx.x : blockIdx.x - 625;
  if (scalarHalf) {
    int col = threadIdx.x & 63, p = col >> 5, w = col & 31;
    int k0 = (threadIdx.x >> 6) * 72;
    for (int k = k0; k < k0 + 72; k++) {
      float v = (k < 256) ? W1[(k >> 5)*4096 + p*1024 + (k & 31)*32 + w]
                          : b1[p*1024 + (k - 256)*32 + w];
      B[col*296 + k] = f2bf(v);
    }
  } else {
    int col = threadIdx.x & 63;
    int base = (col < 32) ? (2048 + col) : (3072 + (col - 32));
    int k0 = (threadIdx.x >> 6) * 72;
    for (int k = k0; k < k0 + 72; k++) {
      float v = (k < 256) ? W1[(k >> 5)*4096 + base + (k & 31)*32]
                          : b1[base + (k - 256)*32];
      B[col*296 + k] = f2bf(v);
    }
  }
  __syncthreads();
  int tile = blk*4 + (threadIdx.x >> 6);
  if (tile*16 >= NE) return;
  int lane = threadIdx.x & 63;
  int m = lane & 15, q = lane >> 4;
  int e = tile*16 + m;
  int srcn = eidx[e];
  float4 hA = *(const float4*)&hE[e*8];
  float4 hB = *(const float4*)&hE[e*8 + 4];
  float hf[8] = {hA.x,hA.y,hA.z,hA.w,hB.x,hB.y,hB.z,hB.w};
  const float c = 0.125f;  // 1/sqrt(64)

  if (scalarHalf) {
    float4 sA = *(const float4*)&s1[srcn*32 + q*8];
    float4 sB = *(const float4*)&s1[srcn*32 + q*8 + 4];
    float sf[8] = {sA.x,sA.y,sA.z,sA.w,sB.x,sB.y,sB.z,sB.w};
    f32x4 acc0 = {0.f,0.f,0.f,0.f}, acc1 = acc0, acc2 = acc0, acc3 = acc0;
#pragma unroll
    for (int ks = 0; ks < 9; ks++) {
      float hs = (ks < 8) ? hf[ks] : 1.f;
      float pr[8];
#pragma unroll
      for (int j = 0; j < 8; j++) pr[j] = hs * sf[j];
      ABfrag ahi, alo;
      pksplit8(pr, ahi, alo);
      int kb = ks*32 + q*8;
      ABfrag b0, b1f, b2, b3;
      b0.q  = *(const uint4*)&B[( 0 + m)*296 + kb];
      b1f.q = *(const uint4*)&B[(16 + m)*296 + kb];
      b2.q  = *(const uint4*)&B[(32 + m)*296 + kb];
      b3.q  = *(const uint4*)&B[(48 + m)*296 + kb];
      acc0 = __builtin_amdgcn_mfma_f32_16x16x32_bf16(ahi.v, b0.v,  acc0, 0, 0, 0);
      acc0 = __builtin_amdgcn_mfma_f32_16x16x32_bf16(alo.v, b0.v,  acc0, 0, 0, 0);
      acc1 = __builtin_amdgcn_mfma_f32_16x16x32_bf16(ahi.v, b1f.v, acc1, 0, 0, 0);
      acc1 = __builtin_amdgcn_mfma_f32_16x16x32_bf16(alo.v, b1f.v, acc1, 0, 0, 0);
      acc2 = __builtin_amdgcn_mfma_f32_16x16x32_bf16(ahi.v, b2.v,  acc2, 0, 0, 0);
      acc2 = __builtin_amdgcn_mfma_f32_16x16x32_bf16(alo.v, b2.v,  acc2, 0, 0, 0);
      acc3 = __builtin_amdgcn_mfma_f32_16x16x32_bf16(ahi.v, b3.v,  acc3, 0, 0, 0);
      acc3 = __builtin_amdgcn_mfma_f32_16x16x32_bf16(alo.v, b3.v,  acc3, 0, 0, 0);
    }
#pragma unroll
    for (int r = 0; r < 4; r++) {
      int et = tile*16 + q*4 + r;
      u16* mp = msgA + (size_t)et*128;
      mp[m]      = f2bf(c*acc0[r]);
      mp[16 + m] = f2bf(c*acc1[r]);
      float s0v = sh[et*3+0], s1v = sh[et*3+1], s2v = sh[et*3+2];
      float m0 = c*acc2[r], m1 = c*acc3[r];
      mp[32 +      m] = f2bf(m0*s0v);
      mp[64 +      m] = f2bf(m0*s1v);
      mp[96 +      m] = f2bf(m0*s2v);
      mp[32 + 16 + m] = f2bf(m1*s0v);
      mp[64 + 16 + m] = f2bf(m1*s1v);
      mp[96 + 16 + m] = f2bf(m1*s2v);
    }
  } else {
    const float is3 = 0.5773502691896258f;
    float vf[3][8];
#pragma unroll
    for (int i = 0; i < 3; i++) {
      float4 aa = *(const float4*)&v1soa[i*160000 + srcn*32 + q*8];
      float4 bb = *(const float4*)&v1soa[i*160000 + srcn*32 + q*8 + 4];
      vf[i][0]=aa.x; vf[i][1]=aa.y; vf[i][2]=aa.z; vf[i][3]=aa.w;
      vf[i][4]=bb.x; vf[i][5]=bb.y; vf[i][6]=bb.z; vf[i][7]=bb.w;
    }
    float es0 = sh[e*3+0], es1 = sh[e*3+1], es2 = sh[e*3+2];
    float df[8];
#pragma unroll
    for (int j = 0; j < 8; j++)
      df[j] = (vf[0][j]*es0 + vf[1][j]*es1 + vf[2][j]*es2) * is3;
    f32x4 z = {0.f,0.f,0.f,0.f};
    f32x4 aV00 = z, aV01 = z, aV10 = z, aV11 = z, aV20 = z, aV21 = z, aD0 = z, aD1 = z;
#pragma unroll
    for (int ks = 0; ks < 9; ks++) {
      int kb = ks*32 + q*8;
      ABfrag b0, b1f, b2, b3;
      b0.q  = *(const uint4*)&B[( 0 + m)*296 + kb];
      b1f.q = *(const uint4*)&B[(16 + m)*296 + kb];
      b2.q  = *(const uint4*)&B[(32 + m)*296 + kb];
      b3.q  = *(const uint4*)&B[(48 + m)*296 + kb];
      float hs = (ks < 8) ? hf[ks] : 1.f;
      float pr[8];
      ABfrag hi, lo;
#pragma unroll
      for (int j = 0; j < 8; j++) pr[j] = hs * vf[0][j];
      pksplit8(pr, hi, lo);
      aV00 = __builtin_amdgcn_mfma_f32_16x16x32_bf16(hi.v, b0.v,  aV00, 0, 0, 0);
      aV00 = __builtin_amdgcn_mfma_f32_16x16x32_bf16(lo.v, b0.v,  aV00, 0, 0, 0);
      aV01 = __builtin_amdgcn_mfma_f32_16x16x32_bf16(hi.v, b1f.v, aV01, 0, 0, 0);
      aV01 = __builtin_amdgcn_mfma_f32_16x16x32_bf16(lo.v, b1f.v, aV01, 0, 0, 0);
#pragma unroll
      for (int j = 0; j < 8; j++) pr[j] = hs * vf[1][j];
      pksplit8(pr, hi, lo);
      aV10 = __builtin_amdgcn_mfma_f32_16x16x32_bf16(hi.v, b0.v,  aV10, 0, 0, 0);
      aV10 = __builtin_amdgcn_mfma_f32_16x16x32_bf16(lo.v, b0.v,  aV10, 0, 0, 0);
      aV11 = __builtin_amdgcn_mfma_f32_16x16x32_bf16(hi.v, b1f.v, aV11, 0, 0, 0);
      aV11 = __builtin_amdgcn_mfma_f32_16x16x32_bf16(lo.v, b1f.v, aV11, 0, 0, 0);
#pragma unroll
      for (int j = 0; j < 8; j++) pr[j] = hs * vf[2][j];
      pksplit8(pr, hi, lo);
      aV20 = __builtin_amdgcn_mfma_f32_16x16x32_bf16(hi.v, b0.v,  aV20, 0, 0, 0);
      aV20 = __builtin_amdgcn_mfma_f32_16x16x32_bf16(lo.v, b0.v,  aV20, 0, 0, 0);
      aV21 = __builtin_amdgcn_mfma_f32_16x16x32_bf16(hi.v, b1f.v, aV21, 0, 0, 0);
      aV21 = __builtin_amdgcn_mfma_f32_16x16x32_bf16(lo.v, b1f.v, aV21, 0, 0, 0);
#pragma unroll
      for (int j = 0; j < 8; j++) pr[j] = hs * df[j];
      pksplit8(pr, hi, lo);
      aD0  = __builtin_amdgcn_mfma_f32_16x16x32_bf16(hi.v, b2.v,  aD0,  0, 0, 0);
      aD0  = __builtin_amdgcn_mfma_f32_16x16x32_bf16(lo.v, b2.v,  aD0,  0, 0, 0);
      aD1  = __builtin_amdgcn_mfma_f32_16x16x32_bf16(hi.v, b3.v,  aD1,  0, 0, 0);
      aD1  = __builtin_amdgcn_mfma_f32_16x16x32_bf16(lo.v, b3.v,  aD1,  0, 0, 0);
    }
#pragma unroll
    for (int r = 0; r < 4; r++) {
      int et = tile*16 + q*4 + r;
      u16* mp = msgB + (size_t)et*128;
      mp[m]      = f2bf(c*aD0[r]);
      mp[16 + m] = f2bf(c*aD1[r]);
      mp[32 +      m] = f2bf(c*aV00[r]);
      mp[32 + 16 + m] = f2bf(c*aV01[r]);
      mp[64 +      m] = f2bf(c*aV10[r]);
      mp[64 + 16 + m] = f2bf(c*aV11[r]);
      mp[96 +      m] = f2bf(c*aV20[r]);
      mp[96 + 16 + m] = f2bf(c*aV21[r]);
    }
  }
}

// ---- gather + mean (conv1); v1 written in SoA [i][n][u] ----
__global__ void k_gather1(const u16* __restrict__ msg, const int* __restrict__ perm,
                          const int* __restrict__ cur, float* __restrict__ s1,
                          float* __restrict__ v1soa) {
  int t = blockIdx.x * blockDim.x + threadIdx.x;
  int n = t >> 7, c = t & 127;
  if (n >= NN) return;
  int deg = min(cur[n], 64);
  float acc = 0.f;
  for (int j = 0; j < deg; j++) {
    int e = perm[n*64 + j];
    acc += bf2f(msg[(size_t)e*128 + c]);
  }
  acc /= (float)max(deg, 1);
  if (c < 32) s1[n*32 + c] = acc;
  else { int i = (c-32) >> 5, w = (c-32) & 31; v1soa[i*160000 + n*32 + w] = acc; }
}

// ---- gather + mean (conv2) + linear self-interaction + node-output MLP (fused) ----
__global__ __launch_bounds__(256) void k_gather2(
    const u16* __restrict__ msgA, const u16* __restrict__ msgB,
    const int* __restrict__ perm, const int* __restrict__ cur,
    const float* __restrict__ s1, const float* __restrict__ v1soa,
    const float* __restrict__ Ws, const float* __restrict__ Wv,
    const float* __restrict__ noW1, const float* __restrict__ noW2,
    float* __restrict__ s2, float* __restrict__ v2, float* __restrict__ outN) {
  __shared__ float sb[2][32];
  __shared__ float hb[2][13];
  int t = blockIdx.x * blockDim.x + threadIdx.x;
  int n = t >> 7, c = t & 127;
  int ln = (threadIdx.x >> 7);
  int deg = min(cur[n], 64);
  float acc = 0.f;
  for (int j = 0; j < deg; j++) {
    int e = perm[n*64 + j];
    acc += bf2f(msgA[(size_t)e*128 + c]) + bf2f(msgB[(size_t)e*128 + c]);
  }
  acc /= (float)max(deg, 1);
  const float lc = 0.17677669529663687f;  // 1/sqrt(32)
  if (c < 32) {
    float ss = 0.f;
#pragma unroll 8
    for (int u = 0; u < 32; u++) ss += s1[n*32 + u] * Ws[u*32 + c];
    float val = acc + lc*ss;
    s2[n*32 + c] = val;
    sb[ln][c] = val;
  } else {
    int i = (c-32) >> 5, w = (c-32) & 31;
    float sv = 0.f;
#pragma unroll 8
    for (int u = 0; u < 32; u++) sv += v1soa[i*160000 + n*32 + u] * Wv[u*32 + w];
    v2[n*96 + w*3 + i] = acc + lc*sv;
  }
  __syncthreads();
  // fused node-output MLP: threads c<13 per node
  const float i32 = 0.17677669529663687f;
  if (c < 13) {
    float a = 0.f;
#pragma unroll 8
    for (int u = 0; u < 32; u++) a += sb[ln][u] * noW1[u*13 + c];
    hb[ln][c] = siluf(a * i32);
  }
  __syncthreads();
  const float i13 = 0.2773500981126146f;  // 1/sqrt(13)
  if (c < 13) {
    float a = 0.f;
#pragma unroll
    for (int j = 0; j < 13; j++) a += hb[ln][j] * noW2[j*13 + c];
    outN[n*13 + c] = a * i13;
  }
}

// ---- edge output TP -> 5x0e; lanes = u, 2 edges per pass, path-major inner loop ----
__global__ __launch_bounds__(256) void k_e3(
    const float* __restrict__ hE, const float* __restrict__ sh,
    const float* __restrict__ s2, const float* __restrict__ v2,
    const int* __restrict__ eidx,
    const float* __restrict__ W1, const float* __restrict__ b1,
    float* __restrict__ out) {
  __shared__ uint4 WQ[640];   // [(p*5+w)*32 + u] : 8 bf16 k-values
  __shared__ float BQ[640];
  for (int t = threadIdx.x; t < 640; t += 256) {
    int u = t & 31, pw = t >> 5, p2 = pw / 5, w = pw - p2*5;
    int col = p2*160 + u*5 + w;
    const float* s = W1 + col;
    uint4 q;
    q.x = packbf2(s[0],      s[640]);
    q.y = packbf2(s[1280],   s[1920]);
    q.z = packbf2(s[2560],   s[3200]);
    q.w = packbf2(s[3840],   s[4480]);
    WQ[t] = q;
    BQ[t] = b1[col];
  }
  __syncthreads();
  const int g = threadIdx.x >> 5, tw = threadIdx.x & 31;
  const float c = 0.08838834764831845f;   // 1/sqrt(128)
  const float is3 = 0.5773502691896258f;
  for (int p = blockIdx.x*8 + g; p*2 < NE; p += gridDim.x*8) {
    int e0 = p*2, e1 = e0 + 1;
    float h0[8], h1[8];
    {
      float4 qa = *(const float4*)&hE[e0*8];
      float4 qb = *(const float4*)&hE[e0*8+4];
      h0[0]=qa.x; h0[1]=qa.y; h0[2]=qa.z; h0[3]=qa.w;
      h0[4]=qb.x; h0[5]=qb.y; h0[6]=qb.z; h0[7]=qb.w;
      float4 qc = *(const float4*)&hE[e1*8];
      float4 qd = *(const float4*)&hE[e1*8+4];
      h1[0]=qc.x; h1[1]=qc.y; h1[2]=qc.z; h1[3]=qc.w;
      h1[4]=qd.x; h1[5]=qd.y; h1[6]=qd.z; h1[7]=qd.w;
    }
    int sA = eidx[e0], dA = eidx[NE+e0];
    int sB = eidx[e1], dB = eidx[NE+e1];
    float sa0 = sh[e0*3+0], sa1 = sh[e0*3+1], sa2 = sh[e0*3+2];
    float sb0 = sh[e1*3+0], sb1 = sh[e1*3+1], sb2 = sh[e1*3+2];
    float c00 = s2[sA*32 + tw];
    float c01 = (v2[sA*96+tw*3+0]*sa0 + v2[sA*96+tw*3+1]*sa1 + v2[sA*96+tw*3+2]*sa2) * is3;
    float c02 = s2[dA*32 + tw];
    float c03 = (v2[dA*96+tw*3+0]*sa0 + v2[dA*96+tw*3+1]*sa1 + v2[dA*96+tw*3+2]*sa2) * is3;
    float c10 = s2[sB*32 + tw];
    float c11 = (v2[sB*96+tw*3+0]*sb0 + v2[sB*96+tw*3+1]*sb1 + v2[sB*96+tw*3+2]*sb2) * is3;
    float c12 = s2[dB*32 + tw];
    float c13 = (v2[dB*96+tw*3+0]*sb0 + v2[dB*96+tw*3+1]*sb1 + v2[dB*96+tw*3+2]*sb2) * is3;
    float part0[5] = {0,0,0,0,0};
    float part1[5] = {0,0,0,0,0};
#pragma unroll
    for (int pp = 0; pp < 4; pp++) {
      float cp0 = (pp==0) ? c00 : (pp==1) ? c01 : (pp==2) ? c02 : c03;
      float cp1 = (pp==0) ? c10 : (pp==1) ? c11 : (pp==2) ? c12 : c13;
#pragma unroll
      for (int w = 0; w < 5; w++) {
        int idx = (pp*5 + w)*32 + tw;
        float f[8];
        unpack8(WQ[idx], f);
        float bv = BQ[idx];
        part0[w] = fmaf(cp0, dot8f(h0, f, bv), part0[w]);
        part1[w] = fmaf(cp1, dot8f(h1, f, bv), part1[w]);
      }
    }
#pragma unroll
    for (int off = 16; off > 0; off >>= 1)
#pragma unroll
      for (int w = 0; w < 5; w++) {
        part0[w] += __shfl_xor(part0[w], off, 32);
        part1[w] += __shfl_xor(part1[w], off, 32);
      }
    float outv = 0.f;
#pragma unroll
    for (int w = 0; w < 5; w++) {
      if (tw == w)     outv = part0[w];
      if (tw == 5 + w) outv = part1[w];
    }
    if (tw < 10) out[e0*5 + tw] = c * outv;
  }
}

extern "C" void kernel_launch(void* const* d_in, const int* in_sizes, int n_in,
                              void* d_out, int out_size, void* d_ws, size_t ws_size,
                              hipStream_t stream) {
  (void)in_sizes; (void)n_in; (void)out_size; (void)ws_size;
  const float* coords = (const float*)d_in[0];
  const int*   atype  = (const int*)d_in[1];
  const int*   eidx   = (const int*)d_in[2];
  const float* emb    = (const float*)d_in[3];
  const float* ipW0 = (const float*)d_in[4];
  const float* ipb0 = (const float*)d_in[5];
  const float* ipW1 = (const float*)d_in[6];
  const float* ipb1 = (const float*)d_in[7];
  const float* lyW0 = (const float*)d_in[8];
  const float* lyb0 = (const float*)d_in[9];
  const float* lyW1 = (const float*)d_in[10];
  const float* lyb1 = (const float*)d_in[11];
  const float* lyWs = (const float*)d_in[12];
  const float* lyWv = (const float*)d_in[13];
  const float* etW0 = (const float*)d_in[14];
  const float* etb0 = (const float*)d_in[15];
  const float* etW1 = (const float*)d_in[16];
  const float* etb1 = (const float*)d_in[17];
  const float* noW1 = (const float*)d_in[18];
  const float* noW2 = (const float*)d_in[19];

  float* ws = (float*)d_ws;
  float* sh    = ws;                  // E*3  = 120000
  float* h_ip  = ws + 120000;         // E*8
  float* h_ly  = ws + 440000;         // E*8
  float* h_et  = ws + 760000;         // E*8
  float* s1    = ws + 1240000;        // N*32
  float* v1soa = ws + 1400000;        // 3 planes of 160000 (SoA)
  float* s2    = ws + 1880000;        // N*32
  float* v2    = ws + 2040000;        // N*96 (AoS)  -> ends 2520000
  int*   cur   = (int*)(ws + 2520000);   // N ints (zeroed)
  int*   perm  = (int*)(ws + 2525000);   // N*64 ints -> ends 2845000
  u16*   msgA  = (u16*)(ws + 2845000);   // E*128 bf16
  u16*   msgB  = (u16*)(ws + 5405000);   // E*128 bf16 -> ends 7965000 floats

  float* outE = (float*)d_out;            // E*5
  float* outN = (float*)d_out + NE*5;     // N*13

  hipMemsetAsync(cur, 0, (size_t)NN * sizeof(int), stream);
  k_geom<<<(NE + 255)/256, 256, 0, stream>>>(coords, eidx, ipW0, ipb0, lyW0, lyb0,
                                             etW0, etb0, sh, h_ip, h_ly, h_et, cur, perm);
  // conv1: FCTP(32x0e, 0e+1o -> 32x0e+32x1o), c = 1/sqrt(32); embedding gather fused
  k_mconv1<<<625, 256, 0, stream>>>(h_ip, sh, emb, atype, eidx, ipW1, ipb1, 2048,
                                    0.17677669529663687f, msgA);
  k_gather1<<<(NN*128 + 255)/256, 256, 0, stream>>>(msgA, perm, cur, s1, v1soa);
  // conv2, both halves in one dispatch
  k_conv2<<<1250, 256, 0, stream>>>(h_ly, sh, s1, v1soa, eidx, lyW1, lyb1, msgA, msgB);
  k_gather2<<<2500, 256, 0, stream>>>(msgA, msgB, perm, cur, s1, v1soa,
                                      lyWs, lyWv, noW1, noW2, s2, v2, outN);
  k_e3<<<1024, 256, 0, stream>>>(h_et, sh, s2, v2, eidx, etW1, etb1, outE);
}

// Round 10
// 191.683 us; speedup vs baseline: 2.0356x; 1.0701x over previous
//
#include <hip/hip_runtime.h>

#define NN 5000
#define NE 40000

typedef unsigned int u32;
typedef unsigned short u16;
typedef __fp16 h16x2 __attribute__((ext_vector_type(2)));
typedef _Float16 f16x8 __attribute__((ext_vector_type(8)));
typedef __attribute__((ext_vector_type(4))) float f32x4;

union AF { u32 u[4]; f16x8 v; uint4 q; };

__device__ __forceinline__ float siluf(float x) { return x / (1.f + __expf(-x)); }

__device__ __forceinline__ u32 f2bf_u(float f) {
  u32 x = __float_as_uint(f);
  return (x + 0x7FFFu + ((x >> 16) & 1u)) >> 16;  // RNE
}
__device__ __forceinline__ u16 f2bf(float f) { return (u16)f2bf_u(f); }
__device__ __forceinline__ float bf2f(u16 v) { return __uint_as_float(((u32)v) << 16); }
__device__ __forceinline__ u32 packbf2(float lo, float hi) {
  return f2bf_u(lo) | (f2bf_u(hi) << 16);
}
// pack 2 floats -> 2 f16 (v_cvt_pkrtz_f16_f32, single VALU op)
__device__ __forceinline__ u32 pkh2(float a, float b) {
  union { h16x2 h; u32 u; } r;
  r.h = __builtin_amdgcn_cvt_pkrtz(a, b);
  return r.u;
}
__device__ __forceinline__ u16 f2h(float v) {
  _Float16 h = (_Float16)v;   // v_cvt_f16_f32, RNE
  return *(u16*)&h;
}
__device__ __forceinline__ void unpack8(uint4 q, float* f) {
  f[0] = __uint_as_float(q.x << 16); f[1] = __uint_as_float(q.x & 0xFFFF0000u);
  f[2] = __uint_as_float(q.y << 16); f[3] = __uint_as_float(q.y & 0xFFFF0000u);
  f[4] = __uint_as_float(q.z << 16); f[5] = __uint_as_float(q.z & 0xFFFF0000u);
  f[6] = __uint_as_float(q.w << 16); f[7] = __uint_as_float(q.w & 0xFFFF0000u);
}
__device__ __forceinline__ float dot8f(const float* h, const float* w, float init) {
  float a = init;
#pragma unroll
  for (int k = 0; k < 8; k++) a = fmaf(h[k], w[k], a);
  return a;
}
__device__ __forceinline__ void mlp8(const float* ea, const float* __restrict__ W0,
                                     const float* __restrict__ b0, float* h) {
#pragma unroll
  for (int j = 0; j < 8; j++) {
    float a = b0[j];
#pragma unroll
    for (int i = 0; i < 8; i++) a += ea[i] * W0[i*8 + j];
    h[j] = siluf(a);
  }
}
// build f16 A-fragment: a = pk(hs * s[0..7])
__device__ __forceinline__ AF mkfrag(float hs, const float* s) {
  AF a;
  a.u[0] = pkh2(hs*s[0], hs*s[1]);
  a.u[1] = pkh2(hs*s[2], hs*s[3]);
  a.u[2] = pkh2(hs*s[4], hs*s[5]);
  a.u[3] = pkh2(hs*s[6], hs*s[7]);
  return a;
}

// ---- geometry + 3 radial-MLP activations + bucket fill (fused) ----
__global__ void k_geom(const float* __restrict__ coords, const int* __restrict__ eidx,
                       const float* __restrict__ ipW0, const float* __restrict__ ipb0,
                       const float* __restrict__ lyW0, const float* __restrict__ lyb0,
                       const float* __restrict__ etW0, const float* __restrict__ etb0,
                       float* __restrict__ sh, float* __restrict__ h_ip,
                       float* __restrict__ h_ly, float* __restrict__ h_et,
                       int* __restrict__ cur, int* __restrict__ perm) {
  int e = blockIdx.x * blockDim.x + threadIdx.x;
  if (e >= NE) return;
  int s = eidx[e], d = eidx[NE + e];
  float vx = coords[d*3+0] - coords[s*3+0];
  float vy = coords[d*3+1] - coords[s*3+1];
  float vz = coords[d*3+2] - coords[s*3+2];
  float dist = sqrtf(vx*vx + vy*vy + vz*vz + 1e-12f);
  float inv = 1.f / dist;
  const float SQ3 = 1.7320508075688772f;
  sh[e*3+0] = SQ3 * vy * inv;   // e3nn (y,z,x) order
  sh[e*3+1] = SQ3 * vz * inv;
  sh[e*3+2] = SQ3 * vx * inv;
  float ea[8];
  const float step = 5.f / 9.f;
#pragma unroll
  for (int j = 0; j < 8; j++) {
    float diff = (dist - step * (float)(j+1)) * (9.f / 5.f);
    ea[j] = __expf(-diff*diff) * (1.f / 1.12f);
  }
  float h[8];
  mlp8(ea, ipW0, ipb0, h);
#pragma unroll
  for (int j = 0; j < 8; j++) h_ip[e*8+j] = h[j];
  mlp8(ea, lyW0, lyb0, h);
#pragma unroll
  for (int j = 0; j < 8; j++) h_ly[e*8+j] = h[j];
  mlp8(ea, etW0, etb0, h);
#pragma unroll
  for (int j = 0; j < 8; j++) h_et[e*8+j] = h[j];
  int t = atomicAdd(&cur[d], 1);
  if (t < 64) perm[d*64 + t] = e;
}

// ---- MFMA conv1 (f16): GEMM [E x 288] @ [288 x 64], Z = [h (x) s_src, s_src] ----
// B2 layout: chunk-major f16, entry ((k>>3)*64 + col)*8 + (k&7) -> contiguous 16B/lane reads.
__global__ __launch_bounds__(256) void k_mconv1(
    const float* __restrict__ hE, const float* __restrict__ sh,
    const float* __restrict__ sIn, const int* __restrict__ atype,
    const int* __restrict__ eidx,
    const float* __restrict__ W1, const float* __restrict__ b1,
    int ldw, float cscale, u16* __restrict__ msg) {
  __shared__ __align__(16) u16 B2[36*64*8];   // 36 KB
  {
    int col = threadIdx.x & 63, p = col >> 5, w = col & 31;
    int k0 = (threadIdx.x >> 6) * 72;
    for (int k = k0; k < k0 + 72; k++) {
      float v = (k < 256) ? W1[(k >> 5)*ldw + p*1024 + (k & 31)*32 + w]
                          : b1[p*1024 + (k - 256)*32 + w];
      B2[((k >> 3)*64 + col)*8 + (k & 7)] = f2h(v);
    }
  }
  __syncthreads();
  int lane = threadIdx.x & 63;
  int m = lane & 15, q = lane >> 4, wid = threadIdx.x >> 6;
  for (int tile = blockIdx.x*4 + wid; tile*16 < NE; tile += gridDim.x*4) {
    int e = tile*16 + m;
    int srcn = eidx[e];
    int srow = atype ? atype[srcn] : srcn;
    float4 sA = *(const float4*)&sIn[srow*32 + q*8];
    float4 sB = *(const float4*)&sIn[srow*32 + q*8 + 4];
    float4 hA = *(const float4*)&hE[e*8];
    float4 hB = *(const float4*)&hE[e*8 + 4];
    float sf[8] = {sA.x,sA.y,sA.z,sA.w,sB.x,sB.y,sB.z,sB.w};
    float hf[8] = {hA.x,hA.y,hA.z,hA.w,hB.x,hB.y,hB.z,hB.w};
    f32x4 acc0 = {0.f,0.f,0.f,0.f}, acc1 = acc0, acc2 = acc0, acc3 = acc0;
#pragma unroll
    for (int ks = 0; ks < 9; ks++) {
      float hs = (ks < 8) ? hf[ks] : 1.f;
      AF a = mkfrag(hs, sf);
      int c2 = (ks*4 + q)*64;
      AF b0, b1f, b2, b3;
      b0.q  = *(const uint4*)&B2[(c2 +  0 + m)*8];
      b1f.q = *(const uint4*)&B2[(c2 + 16 + m)*8];
      b2.q  = *(const uint4*)&B2[(c2 + 32 + m)*8];
      b3.q  = *(const uint4*)&B2[(c2 + 48 + m)*8];
      acc0 = __builtin_amdgcn_mfma_f32_16x16x32_f16(a.v, b0.v,  acc0, 0, 0, 0);
      acc1 = __builtin_amdgcn_mfma_f32_16x16x32_f16(a.v, b1f.v, acc1, 0, 0, 0);
      acc2 = __builtin_amdgcn_mfma_f32_16x16x32_f16(a.v, b2.v,  acc2, 0, 0, 0);
      acc3 = __builtin_amdgcn_mfma_f32_16x16x32_f16(a.v, b3.v,  acc3, 0, 0, 0);
    }
    // C/D: col = lane&15 (= channel), row = q*4+r (= edge within tile)
#pragma unroll
    for (int r = 0; r < 4; r++) {
      int et = tile*16 + q*4 + r;
      u16* mp = msg + (size_t)et*128;
      mp[m]      = f2bf(cscale*acc0[r]);
      mp[16 + m] = f2bf(cscale*acc1[r]);
      float s0v = sh[et*3+0], s1v = sh[et*3+1], s2v = sh[et*3+2];
      float m0 = cscale*acc2[r], m1 = cscale*acc3[r];
      mp[32 +      m] = f2bf(m0*s0v);
      mp[64 +      m] = f2bf(m0*s1v);
      mp[96 +      m] = f2bf(m0*s2v);
      mp[32 + 16 + m] = f2bf(m1*s0v);
      mp[64 + 16 + m] = f2bf(m1*s1v);
      mp[96 + 16 + m] = f2bf(m1*s2v);
    }
  }
}

// ---- conv2 (f16), single dispatch: blocks [0,HB) scalar paths {0,1} -> msgA;
//      blocks [HB,2*HB) vector paths {2,3} -> msgB ----
#define HB 320
__global__ __launch_bounds__(256) void k_conv2(
    const float* __restrict__ hE, const float* __restrict__ sh,
    const float* __restrict__ s1, const float* __restrict__ v1soa,
    const int* __restrict__ eidx,
    const float* __restrict__ W1, const float* __restrict__ b1,
    u16* __restrict__ msgA, u16* __restrict__ msgB) {
  __shared__ __align__(16) u16 B2[36*64*8];
  const bool scalarHalf = blockIdx.x < HB;
  int blk = scalarHalf ? blockIdx.x : blockIdx.x - HB;
  {
    int col = threadIdx.x & 63;
    int base = scalarHalf ? ((col >> 5)*1024 + (col & 31))
                          : ((col < 32) ? (2048 + col) : (3072 + (col - 32)));
    int k0 = (threadIdx.x >> 6) * 72;
    for (int k = k0; k < k0 + 72; k++) {
      float v = (k < 256) ? W1[(k >> 5)*4096 + base + (k & 31)*32]
                          : b1[base + (k - 256)*32];
      B2[((k >> 3)*64 + col)*8 + (k & 7)] = f2h(v);
    }
  }
  __syncthreads();
  int lane = threadIdx.x & 63;
  int m = lane & 15, q = lane >> 4, wid = threadIdx.x >> 6;
  const float c = 0.125f;  // 1/sqrt(64)
  for (int tile = blk*4 + wid; tile*16 < NE; tile += HB*4) {
    int e = tile*16 + m;
    int srcn = eidx[e];
    float4 hA = *(const float4*)&hE[e*8];
    float4 hB = *(const float4*)&hE[e*8 + 4];
    float hf[8] = {hA.x,hA.y,hA.z,hA.w,hB.x,hB.y,hB.z,hB.w};

    if (scalarHalf) {
      float4 sA = *(const float4*)&s1[srcn*32 + q*8];
      float4 sB = *(const float4*)&s1[srcn*32 + q*8 + 4];
      float sf[8] = {sA.x,sA.y,sA.z,sA.w,sB.x,sB.y,sB.z,sB.w};
      f32x4 acc0 = {0.f,0.f,0.f,0.f}, acc1 = acc0, acc2 = acc0, acc3 = acc0;
#pragma unroll
      for (int ks = 0; ks < 9; ks++) {
        float hs = (ks < 8) ? hf[ks] : 1.f;
        AF a = mkfrag(hs, sf);
        int c2 = (ks*4 + q)*64;
        AF b0, b1f, b2, b3;
        b0.q  = *(const uint4*)&B2[(c2 +  0 + m)*8];
        b1f.q = *(const uint4*)&B2[(c2 + 16 + m)*8];
        b2.q  = *(const uint4*)&B2[(c2 + 32 + m)*8];
        b3.q  = *(const uint4*)&B2[(c2 + 48 + m)*8];
        acc0 = __builtin_amdgcn_mfma_f32_16x16x32_f16(a.v, b0.v,  acc0, 0, 0, 0);
        acc1 = __builtin_amdgcn_mfma_f32_16x16x32_f16(a.v, b1f.v, acc1, 0, 0, 0);
        acc2 = __builtin_amdgcn_mfma_f32_16x16x32_f16(a.v, b2.v,  acc2, 0, 0, 0);
        acc3 = __builtin_amdgcn_mfma_f32_16x16x32_f16(a.v, b3.v,  acc3, 0, 0, 0);
      }
#pragma unroll
      for (int r = 0; r < 4; r++) {
        int et = tile*16 + q*4 + r;
        u16* mp = msgA + (size_t)et*128;
        mp[m]      = f2bf(c*acc0[r]);
        mp[16 + m] = f2bf(c*acc1[r]);
        float s0v = sh[et*3+0], s1v = sh[et*3+1], s2v = sh[et*3+2];
        float m0 = c*acc2[r], m1 = c*acc3[r];
        mp[32 +      m] = f2bf(m0*s0v);
        mp[64 +      m] = f2bf(m0*s1v);
        mp[96 +      m] = f2bf(m0*s2v);
        mp[32 + 16 + m] = f2bf(m1*s0v);
        mp[64 + 16 + m] = f2bf(m1*s1v);
        mp[96 + 16 + m] = f2bf(m1*s2v);
      }
    } else {
      const float is3 = 0.5773502691896258f;
      float vf[3][8];
#pragma unroll
      for (int i = 0; i < 3; i++) {
        float4 aa = *(const float4*)&v1soa[i*160000 + srcn*32 + q*8];
        float4 bb = *(const float4*)&v1soa[i*160000 + srcn*32 + q*8 + 4];
        vf[i][0]=aa.x; vf[i][1]=aa.y; vf[i][2]=aa.z; vf[i][3]=aa.w;
        vf[i][4]=bb.x; vf[i][5]=bb.y; vf[i][6]=bb.z; vf[i][7]=bb.w;
      }
      float es0 = sh[e*3+0], es1 = sh[e*3+1], es2 = sh[e*3+2];
      float df[8];
#pragma unroll
      for (int j = 0; j < 8; j++)
        df[j] = (vf[0][j]*es0 + vf[1][j]*es1 + vf[2][j]*es2) * is3;
      f32x4 z = {0.f,0.f,0.f,0.f};
      f32x4 aV00 = z, aV01 = z, aV10 = z, aV11 = z, aV20 = z, aV21 = z, aD0 = z, aD1 = z;
#pragma unroll
      for (int ks = 0; ks < 9; ks++) {
        float hs = (ks < 8) ? hf[ks] : 1.f;
        int c2 = (ks*4 + q)*64;
        AF b0, b1f, b2, b3;
        b0.q  = *(const uint4*)&B2[(c2 +  0 + m)*8];
        b1f.q = *(const uint4*)&B2[(c2 + 16 + m)*8];
        b2.q  = *(const uint4*)&B2[(c2 + 32 + m)*8];
        b3.q  = *(const uint4*)&B2[(c2 + 48 + m)*8];
        AF a0 = mkfrag(hs, vf[0]);
        AF a1 = mkfrag(hs, vf[1]);
        AF a2 = mkfrag(hs, vf[2]);
        AF ad = mkfrag(hs, df);
        aV00 = __builtin_amdgcn_mfma_f32_16x16x32_f16(a0.v, b0.v,  aV00, 0, 0, 0);
        aV01 = __builtin_amdgcn_mfma_f32_16x16x32_f16(a0.v, b1f.v, aV01, 0, 0, 0);
        aV10 = __builtin_amdgcn_mfma_f32_16x16x32_f16(a1.v, b0.v,  aV10, 0, 0, 0);
        aV11 = __builtin_amdgcn_mfma_f32_16x16x32_f16(a1.v, b1f.v, aV11, 0, 0, 0);
        aV20 = __builtin_amdgcn_mfma_f32_16x16x32_f16(a2.v, b0.v,  aV20, 0, 0, 0);
        aV21 = __builtin_amdgcn_mfma_f32_16x16x32_f16(a2.v, b1f.v, aV21, 0, 0, 0);
        aD0  = __builtin_amdgcn_mfma_f32_16x16x32_f16(ad.v, b2.v,  aD0,  0, 0, 0);
        aD1  = __builtin_amdgcn_mfma_f32_16x16x32_f16(ad.v, b3.v,  aD1,  0, 0, 0);
      }
#pragma unroll
      for (int r = 0; r < 4; r++) {
        int et = tile*16 + q*4 + r;
        u16* mp = msgB + (size_t)et*128;
        mp[m]      = f2bf(c*aD0[r]);
        mp[16 + m] = f2bf(c*aD1[r]);
        mp[32 +      m] = f2bf(c*aV00[r]);
        mp[32 + 16 + m] = f2bf(c*aV01[r]);
        mp[64 +      m] = f2bf(c*aV10[r]);
        mp[64 + 16 + m] = f2bf(c*aV11[r]);
        mp[96 +      m] = f2bf(c*aV20[r]);
        mp[96 + 16 + m] = f2bf(c*aV21[r]);
      }
    }
  }
}

// ---- gather + mean (conv1); v1 written in SoA [i][n][u] ----
__global__ void k_gather1(const u16* __restrict__ msg, const int* __restrict__ perm,
                          const int* __restrict__ cur, float* __restrict__ s1,
                          float* __restrict__ v1soa) {
  int t = blockIdx.x * blockDim.x + threadIdx.x;
  int n = t >> 7, c = t & 127;
  if (n >= NN) return;
  int deg = min(cur[n], 64);
  float acc = 0.f;
  for (int j = 0; j < deg; j++) {
    int e = perm[n*64 + j];
    acc += bf2f(msg[(size_t)e*128 + c]);
  }
  acc /= (float)max(deg, 1);
  if (c < 32) s1[n*32 + c] = acc;
  else { int i = (c-32) >> 5, w = (c-32) & 31; v1soa[i*160000 + n*32 + w] = acc; }
}

// ---- gather + mean (conv2) + linear self-interaction + node-output MLP (fused) ----
__global__ __launch_bounds__(256) void k_gather2(
    const u16* __restrict__ msgA, const u16* __restrict__ msgB,
    const int* __restrict__ perm, const int* __restrict__ cur,
    const float* __restrict__ s1, const float* __restrict__ v1soa,
    const float* __restrict__ Ws, const float* __restrict__ Wv,
    const float* __restrict__ noW1, const float* __restrict__ noW2,
    float* __restrict__ s2, float* __restrict__ v2, float* __restrict__ outN) {
  __shared__ float sb[2][32];
  __shared__ float hb[2][13];
  int t = blockIdx.x * blockDim.x + threadIdx.x;
  int n = t >> 7, c = t & 127;
  int ln = (threadIdx.x >> 7);
  int deg = min(cur[n], 64);
  float acc = 0.f;
  for (int j = 0; j < deg; j++) {
    int e = perm[n*64 + j];
    acc += bf2f(msgA[(size_t)e*128 + c]) + bf2f(msgB[(size_t)e*128 + c]);
  }
  acc /= (float)max(deg, 1);
  const float lc = 0.17677669529663687f;  // 1/sqrt(32)
  if (c < 32) {
    float ss = 0.f;
#pragma unroll 8
    for (int u = 0; u < 32; u++) ss += s1[n*32 + u] * Ws[u*32 + c];
    float val = acc + lc*ss;
    s2[n*32 + c] = val;
    sb[ln][c] = val;
  } else {
    int i = (c-32) >> 5, w = (c-32) & 31;
    float sv = 0.f;
#pragma unroll 8
    for (int u = 0; u < 32; u++) sv += v1soa[i*160000 + n*32 + u] * Wv[u*32 + w];
    v2[n*96 + w*3 + i] = acc + lc*sv;
  }
  __syncthreads();
  const float i32 = 0.17677669529663687f;
  if (c < 13) {
    float a = 0.f;
#pragma unroll 8
    for (int u = 0; u < 32; u++) a += sb[ln][u] * noW1[u*13 + c];
    hb[ln][c] = siluf(a * i32);
  }
  __syncthreads();
  const float i13 = 0.2773500981126146f;  // 1/sqrt(13)
  if (c < 13) {
    float a = 0.f;
#pragma unroll
    for (int j = 0; j < 13; j++) a += hb[ln][j] * noW2[j*13 + c];
    outN[n*13 + c] = a * i13;
  }
}

// ---- edge output TP -> 5x0e; lanes = u, 2 edges per pass, path-major inner loop ----
__global__ __launch_bounds__(256) void k_e3(
    const float* __restrict__ hE, const float* __restrict__ sh,
    const float* __restrict__ s2, const float* __restrict__ v2,
    const int* __restrict__ eidx,
    const float* __restrict__ W1, const float* __restrict__ b1,
    float* __restrict__ out) {
  __shared__ uint4 WQ[640];   // [(p*5+w)*32 + u] : 8 bf16 k-values
  __shared__ float BQ[640];
  for (int t = threadIdx.x; t < 640; t += 256) {
    int u = t & 31, pw = t >> 5, p2 = pw / 5, w = pw - p2*5;
    int col = p2*160 + u*5 + w;
    const float* s = W1 + col;
    uint4 q;
    q.x = packbf2(s[0],      s[640]);
    q.y = packbf2(s[1280],   s[1920]);
    q.z = packbf2(s[2560],   s[3200]);
    q.w = packbf2(s[3840],   s[4480]);
    WQ[t] = q;
    BQ[t] = b1[col];
  }
  __syncthreads();
  const int g = threadIdx.x >> 5, tw = threadIdx.x & 31;
  const float c = 0.08838834764831845f;   // 1/sqrt(128)
  const float is3 = 0.5773502691896258f;
  for (int p = blockIdx.x*8 + g; p*2 < NE; p += gridDim.x*8) {
    int e0 = p*2, e1 = e0 + 1;
    float h0[8], h1[8];
    {
      float4 qa = *(const float4*)&hE[e0*8];
      float4 qb = *(const float4*)&hE[e0*8+4];
      h0[0]=qa.x; h0[1]=qa.y; h0[2]=qa.z; h0[3]=qa.w;
      h0[4]=qb.x; h0[5]=qb.y; h0[6]=qb.z; h0[7]=qb.w;
      float4 qc = *(const float4*)&hE[e1*8];
      float4 qd = *(const float4*)&hE[e1*8+4];
      h1[0]=qc.x; h1[1]=qc.y; h1[2]=qc.z; h1[3]=qc.w;
      h1[4]=qd.x; h1[5]=qd.y; h1[6]=qd.z; h1[7]=qd.w;
    }
    int sA = eidx[e0], dA = eidx[NE+e0];
    int sB = eidx[e1], dB = eidx[NE+e1];
    float sa0 = sh[e0*3+0], sa1 = sh[e0*3+1], sa2 = sh[e0*3+2];
    float sb0 = sh[e1*3+0], sb1 = sh[e1*3+1], sb2 = sh[e1*3+2];
    float c00 = s2[sA*32 + tw];
    float c01 = (v2[sA*96+tw*3+0]*sa0 + v2[sA*96+tw*3+1]*sa1 + v2[sA*96+tw*3+2]*sa2) * is3;
    float c02 = s2[dA*32 + tw];
    float c03 = (v2[dA*96+tw*3+0]*sa0 + v2[dA*96+tw*3+1]*sa1 + v2[dA*96+tw*3+2]*sa2) * is3;
    float c10 = s2[sB*32 + tw];
    float c11 = (v2[sB*96+tw*3+0]*sb0 + v2[sB*96+tw*3+1]*sb1 + v2[sB*96+tw*3+2]*sb2) * is3;
    float c12 = s2[dB*32 + tw];
    float c13 = (v2[dB*96+tw*3+0]*sb0 + v2[dB*96+tw*3+1]*sb1 + v2[dB*96+tw*3+2]*sb2) * is3;
    float part0[5] = {0,0,0,0,0};
    float part1[5] = {0,0,0,0,0};
#pragma unroll
    for (int pp = 0; pp < 4; pp++) {
      float cp0 = (pp==0) ? c00 : (pp==1) ? c01 : (pp==2) ? c02 : c03;
      float cp1 = (pp==0) ? c10 : (pp==1) ? c11 : (pp==2) ? c12 : c13;
#pragma unroll
      for (int w = 0; w < 5; w++) {
        int idx = (pp*5 + w)*32 + tw;
        float f[8];
        unpack8(WQ[idx], f);
        float bv = BQ[idx];
        part0[w] = fmaf(cp0, dot8f(h0, f, bv), part0[w]);
        part1[w] = fmaf(cp1, dot8f(h1, f, bv), part1[w]);
      }
    }
#pragma unroll
    for (int off = 16; off > 0; off >>= 1)
#pragma unroll
      for (int w = 0; w < 5; w++) {
        part0[w] += __shfl_xor(part0[w], off, 32);
        part1[w] += __shfl_xor(part1[w], off, 32);
      }
    float outv = 0.f;
#pragma unroll
    for (int w = 0; w < 5; w++) {
      if (tw == w)     outv = part0[w];
      if (tw == 5 + w) outv = part1[w];
    }
    if (tw < 10) out[e0*5 + tw] = c * outv;
  }
}

extern "C" void kernel_launch(void* const* d_in, const int* in_sizes, int n_in,
                              void* d_out, int out_size, void* d_ws, size_t ws_size,
                              hipStream_t stream) {
  (void)in_sizes; (void)n_in; (void)out_size; (void)ws_size;
  const float* coords = (const float*)d_in[0];
  const int*   atype  = (const int*)d_in[1];
  const int*   eidx   = (const int*)d_in[2];
  const float* emb    = (const float*)d_in[3];
  const float* ipW0 = (const float*)d_in[4];
  const float* ipb0 = (const float*)d_in[5];
  const float* ipW1 = (const float*)d_in[6];
  const float* ipb1 = (const float*)d_in[7];
  const float* lyW0 = (const float*)d_in[8];
  const float* lyb0 = (const float*)d_in[9];
  const float* lyW1 = (const float*)d_in[10];
  const float* lyb1 = (const float*)d_in[11];
  const float* lyWs = (const float*)d_in[12];
  const float* lyWv = (const float*)d_in[13];
  const float* etW0 = (const float*)d_in[14];
  const float* etb0 = (const float*)d_in[15];
  const float* etW1 = (const float*)d_in[16];
  const float* etb1 = (const float*)d_in[17];
  const float* noW1 = (const float*)d_in[18];
  const float* noW2 = (const float*)d_in[19];

  float* ws = (float*)d_ws;
  float* sh    = ws;                  // E*3  = 120000
  float* h_ip  = ws + 120000;         // E*8
  float* h_ly  = ws + 440000;         // E*8
  float* h_et  = ws + 760000;         // E*8
  float* s1    = ws + 1240000;        // N*32
  float* v1soa = ws + 1400000;        // 3 planes of 160000 (SoA)
  float* s2    = ws + 1880000;        // N*32
  float* v2    = ws + 2040000;        // N*96 (AoS)  -> ends 2520000
  int*   cur   = (int*)(ws + 2520000);   // N ints (zeroed)
  int*   perm  = (int*)(ws + 2525000);   // N*64 ints -> ends 2845000
  u16*   msgA  = (u16*)(ws + 2845000);   // E*128 bf16
  u16*   msgB  = (u16*)(ws + 5405000);   // E*128 bf16 -> ends 7965000 floats

  float* outE = (float*)d_out;            // E*5
  float* outN = (float*)d_out + NE*5;     // N*13

  (void)hipMemsetAsync(cur, 0, (size_t)NN * sizeof(int), stream);
  k_geom<<<(NE + 255)/256, 256, 0, stream>>>(coords, eidx, ipW0, ipb0, lyW0, lyb0,
                                             etW0, etb0, sh, h_ip, h_ly, h_et, cur, perm);
  // conv1: FCTP(32x0e, 0e+1o -> 32x0e+32x1o), c = 1/sqrt(32); embedding gather fused
  k_mconv1<<<HB, 256, 0, stream>>>(h_ip, sh, emb, atype, eidx, ipW1, ipb1, 2048,
                                   0.17677669529663687f, msgA);
  k_gather1<<<(NN*128 + 255)/256, 256, 0, stream>>>(msgA, perm, cur, s1, v1soa);
  // conv2, both halves in one dispatch
  k_conv2<<<2*HB, 256, 0, stream>>>(h_ly, sh, s1, v1soa, eidx, lyW1, lyb1, msgA, msgB);
  k_gather2<<<2500, 256, 0, stream>>>(msgA, msgB, perm, cur, s1, v1soa,
                                      lyWs, lyWv, noW1, noW2, s2, v2, outN);
  k_e3<<<1024, 256, 0, stream>>>(h_et, sh, s2, v2, eidx, etW1, etb1, outE);
}